// Round 11
// baseline (387.736 us; speedup 1.0000x reference)
//
#include <hip/hip_runtime.h>
#include <hip/hip_bf16.h>
#include <math.h>

#define N_HEADS 4
#define D_HEAD 32
#define IN_DIM 256
#define OUT_DIM (N_HEADS * D_HEAD)   // 128
#define NEG_SLOPE 0.01f

// CSR-build geometry: 128 nodes per bucket, padded scratch regions.
// NOTE: packing (dst<<16 | src) requires n_nodes < 65536 (here 50000).
#define BSHIFT 7
#define BUCK_NODES 128
#define CAP 4096            // scratch slots per bucket (avg fill ~2048)
#define CHUNK 8192          // edges per pass-A block
#define DBINS 64            // degree bins for node permutation

typedef __attribute__((ext_vector_type(8))) short bf16x8;
typedef __attribute__((ext_vector_type(4))) float f32x4;
typedef __attribute__((ext_vector_type(2))) float f32x2;

// round-to-nearest-even f32 -> bf16 (as u16) — cold path only (setup)
static __device__ __forceinline__ unsigned short f2bf(float x)
{
    unsigned int u = __float_as_uint(x);
    u = u + 0x7FFFu + ((u >> 16) & 1u);
    return (unsigned short)(u >> 16);
}

// hot-path pack: 2 floats -> packed bf16x2 (v_cvt_pk_bf16_f32)
static __device__ __forceinline__ unsigned int pack_bf2(float a, float b)
{
    union { __hip_bfloat162 b2; unsigned int u; } r;
    r.b2 = __float22bfloat162_rn(make_float2(a, b));
    return r.u;
}

static __device__ __forceinline__ float bf_lo(unsigned int u)
{
    return __uint_as_float(u << 16);
}
static __device__ __forceinline__ float bf_hi(unsigned int u)
{
    return __uint_as_float(u & 0xFFFF0000u);
}

static __device__ __forceinline__ f32x2 bfpair(unsigned int u)
{
    f32x2 r;
    r.x = bf_lo(u);
    r.y = bf_hi(u);
    return r;
}

// ---------------------------------------------------------------------------
// setup: arrange fc_w into MFMA-B-fragment order (bf16); zero bucket_fill,
// deg_hist, dfill.
// wl[((cf*8+kf)*64 + l)*8 + j] = B[kf*32 + 8*(l>>4) + j][cf*16 + (l&15)]
// ---------------------------------------------------------------------------
__global__ void setup_kernel(const float* __restrict__ fc_w,
                             unsigned short* __restrict__ wl,
                             int* __restrict__ bucket_fill, int nbuck,
                             int* __restrict__ deg_zero /* deg_hist+dfill, 2*DBINS */)
{
    int o = blockIdx.x * blockDim.x + threadIdx.x;   // 0..32767
    if (o < nbuck) bucket_fill[o] = 0;
    if (o < 2 * DBINS) deg_zero[o] = 0;
    if (o >= 32768) return;
    int j  = o & 7;
    int l  = (o >> 3) & 63;
    int kf = (o >> 9) & 7;
    int cf = (o >> 12) & 7;
    int k   = kf * 32 + (l >> 4) * 8 + j;
    int col = cf * 16 + (l & 15);
    int hh = col >> 5, d = col & 31;
    wl[o] = f2bf(fc_w[hh * 8192 + k * 32 + d]);
}

// ---------------------------------------------------------------------------
// MFMA GEMM: 256 rows/block, 8 waves x 32 rows (2 fragment sets per wave).
// ---------------------------------------------------------------------------
__global__ __launch_bounds__(512, 4) void gemm_mfma_kernel(
    const float* __restrict__ h, const unsigned short* __restrict__ wl,
    const float* __restrict__ attn_w,
    unsigned int* __restrict__ zb,
    float* __restrict__ s_src, float* __restrict__ s_dst,
    int n_nodes)
{
    __shared__ unsigned short wls[32768];   // 64 KB

    const int t = threadIdx.x;

    #pragma unroll
    for (int it = 0; it < 8; ++it) {
        ((uint4*)wls)[t + it * 512] = ((const uint4*)wl)[t + it * 512];
    }
    __syncthreads();

    const int w  = t >> 6;          // wave 0..7
    const int l  = t & 63;
    const int g  = l >> 4;
    const int ln = l & 15;
    const int m0 = blockIdx.x * 256 + w * 32;

    const int arowA = min(m0 + ln,      n_nodes - 1);
    const int arowB = min(m0 + 16 + ln, n_nodes - 1);
    const float4* hrowA = (const float4*)(h + (size_t)arowA * IN_DIM);
    const float4* hrowB = (const float4*)(h + (size_t)arowB * IN_DIM);

    f32x4 accA[8], accB[8];
    #pragma unroll
    for (int cf = 0; cf < 8; ++cf) {
        accA[cf] = (f32x4){0.f, 0.f, 0.f, 0.f};
        accB[cf] = (f32x4){0.f, 0.f, 0.f, 0.f};
    }

    #pragma unroll
    for (int kf = 0; kf < 8; ++kf) {
        float4 a0 = hrowA[kf * 8 + g * 2];
        float4 a1 = hrowA[kf * 8 + g * 2 + 1];
        float4 b0 = hrowB[kf * 8 + g * 2];
        float4 b1 = hrowB[kf * 8 + g * 2 + 1];
        union { unsigned int u[4]; bf16x8 v; } faA, faB;
        faA.u[0] = pack_bf2(a0.x, a0.y);
        faA.u[1] = pack_bf2(a0.z, a0.w);
        faA.u[2] = pack_bf2(a1.x, a1.y);
        faA.u[3] = pack_bf2(a1.z, a1.w);
        faB.u[0] = pack_bf2(b0.x, b0.y);
        faB.u[1] = pack_bf2(b0.z, b0.w);
        faB.u[2] = pack_bf2(b1.x, b1.y);
        faB.u[3] = pack_bf2(b1.z, b1.w);

        #pragma unroll
        for (int cf = 0; cf < 8; ++cf) {
            bf16x8 fb = *(const bf16x8*)&wls[((cf * 8 + kf) * 64 + l) * 8];
            accA[cf] = __builtin_amdgcn_mfma_f32_16x16x32_bf16(faA.v, fb, accA[cf], 0, 0, 0);
            accB[cf] = __builtin_amdgcn_mfma_f32_16x16x32_bf16(faB.v, fb, accB[cf], 0, 0, 0);
        }
    }

    float aw_s[8], aw_d[8];
    #pragma unroll
    for (int cf = 0; cf < 8; ++cf) {
        int col = cf * 16 + ln;
        int hh = col >> 5, d = col & 31;
        aw_s[cf] = attn_w[hh * 64 + d];
        aw_d[cf] = attn_w[hh * 64 + 32 + d];
    }

    #pragma unroll
    for (int set = 0; set < 2; ++set) {
        const int rb = m0 + set * 16;
        #pragma unroll
        for (int r = 0; r < 4; ++r) {
            const int row = rb + 4 * g + r;
            const bool ok = (row < n_nodes);
            f32x4* acc = set ? accB : accA;

            float vs0 = acc[0][r] * aw_s[0] + acc[1][r] * aw_s[1];
            float vs1 = acc[2][r] * aw_s[2] + acc[3][r] * aw_s[3];
            float vs2 = acc[4][r] * aw_s[4] + acc[5][r] * aw_s[5];
            float vs3 = acc[6][r] * aw_s[6] + acc[7][r] * aw_s[7];
            float vd0 = acc[0][r] * aw_d[0] + acc[1][r] * aw_d[1];
            float vd1 = acc[2][r] * aw_d[2] + acc[3][r] * aw_d[3];
            float vd2 = acc[4][r] * aw_d[4] + acc[5][r] * aw_d[5];
            float vd3 = acc[6][r] * aw_d[6] + acc[7][r] * aw_d[7];
            #pragma unroll
            for (int mk = 1; mk < 16; mk <<= 1) {
                vs0 += __shfl_xor(vs0, mk); vs1 += __shfl_xor(vs1, mk);
                vs2 += __shfl_xor(vs2, mk); vs3 += __shfl_xor(vs3, mk);
                vd0 += __shfl_xor(vd0, mk); vd1 += __shfl_xor(vd1, mk);
                vd2 += __shfl_xor(vd2, mk); vd3 += __shfl_xor(vd3, mk);
            }
            float sel_s = (ln == 0) ? vs0 : (ln == 1) ? vs1 : (ln == 2) ? vs2 : vs3;
            float sel_d = ((ln & 3) == 0) ? vd0 : ((ln & 3) == 1) ? vd1 : ((ln & 3) == 2) ? vd2 : vd3;
            if (ok && ln < 4)              s_src[row * N_HEADS + ln]       = sel_s;
            if (ok && ln >= 4 && ln < 8)   s_dst[row * N_HEADS + (ln & 3)] = sel_d;

            #pragma unroll
            for (int cf = 0; cf < 8; ++cf) {
                float v = acc[cf][r];
                float o = __shfl_xor(v, 1);
                if (!(ln & 1) && ok) {
                    zb[(size_t)row * 64 + cf * 8 + (ln >> 1)] = pack_bf2(v, o);
                }
            }
        }
    }
}

// ---------------------------------------------------------------------------
// Pass A: bucket-scatter with LDS aggregation (dense scratch writes).
// ---------------------------------------------------------------------------
__global__ __launch_bounds__(256) void bucketA_kernel(
    const int* __restrict__ src, const int* __restrict__ dst,
    int* __restrict__ bucket_fill, unsigned int* __restrict__ scratch,
    int n_edges, int nbuck)
{
    __shared__ int bhist[512];
    __shared__ int boff[512];
    __shared__ int goff[512];
    __shared__ int bcur[512];
    __shared__ int stmp[256];
    __shared__ unsigned int lpair[CHUNK];   // 32 KB

    const int t  = threadIdx.x;
    const int e0 = blockIdx.x * CHUNK;
    const int n  = min(CHUNK, n_edges - e0);

    bhist[t] = 0; bhist[t + 256] = 0;
    __syncthreads();

    for (int i = t; i < n; i += 256) {
        atomicAdd(&bhist[dst[e0 + i] >> BSHIFT], 1);
    }
    __syncthreads();

    int a0 = bhist[2 * t], a1 = bhist[2 * t + 1];
    int s  = a0 + a1;
    int x  = s;
    stmp[t] = x;
    __syncthreads();
    for (int off = 1; off < 256; off <<= 1) {
        int y = (t >= off) ? stmp[t - off] : 0;
        __syncthreads();
        x += y;
        stmp[t] = x;
        __syncthreads();
    }
    int excl = x - s;
    boff[2 * t]     = excl;
    boff[2 * t + 1] = excl + a0;
    bcur[2 * t]     = excl;
    bcur[2 * t + 1] = excl + a0;

    #pragma unroll
    for (int b = t; b < 512; b += 256) {
        int c = bhist[b];
        goff[b] = (c > 0) ? (b * CAP + atomicAdd(&bucket_fill[b], c)) : 0;
    }
    __syncthreads();

    for (int i = t; i < n; i += 256) {
        int d  = dst[e0 + i];
        int sv = src[e0 + i];
        int p  = atomicAdd(&bcur[d >> BSHIFT], 1);
        lpair[p] = ((unsigned int)d << 16) | (unsigned int)sv;
    }
    __syncthreads();

    const int lim = nbuck * CAP - 1;
    for (int i = t; i < n; i += 256) {
        unsigned int u = lpair[i];
        int b = (int)(u >> 16) >> BSHIFT;
        int addr = goff[b] + (i - boff[b]);
        scratch[min(addr, lim)] = u;
    }
}

// ---------------------------------------------------------------------------
// Pass B (runs AFTER gemm): one block per bucket. Redundant bucket scan ->
// row0; per-node LDS histogram + scan -> row_start + deg_hist; placement
// writes sorted_src AND precomputed softmax numerators ex (bf16x2 pairs):
// ex[edge][h] = exp(leaky(s_src[src][h] + s_dst[dst][h])).
// leaky-relu bounds e in [-0.3, ~7] -> ex in [~0.74, ~1100]: bf16-safe.
// ---------------------------------------------------------------------------
__global__ __launch_bounds__(256) void bucketB_kernel(
    const unsigned int* __restrict__ scratch,
    const int* __restrict__ bucket_fill,
    const float* __restrict__ s_src, const float* __restrict__ s_dst,
    int* __restrict__ row_start,
    int* __restrict__ sorted_src,
    uint2* __restrict__ packed_ex,
    int* __restrict__ deg_hist,
    int n_nodes, int nbuck, int n_edges)
{
    __shared__ int pref[512];
    __shared__ int lhist[128];
    __shared__ int lcur[128];
    __shared__ int stmp[256];
    __shared__ unsigned int ent[CAP];   // 16 KB

    const int b = blockIdx.x;
    const int t = threadIdx.x;

    // --- redundant exclusive scan of bucket_fill -> pref[] ---
    {
        int a0 = (2 * t     < nbuck) ? min(bucket_fill[2 * t],     CAP) : 0;
        int a1 = (2 * t + 1 < nbuck) ? min(bucket_fill[2 * t + 1], CAP) : 0;
        int s = a0 + a1;
        int x = s;
        stmp[t] = x;
        __syncthreads();
        for (int off = 1; off < 256; off <<= 1) {
            int y = (t >= off) ? stmp[t - off] : 0;
            __syncthreads();
            x += y;
            stmp[t] = x;
            __syncthreads();
        }
        int excl = x - s;
        pref[2 * t]     = excl;
        pref[2 * t + 1] = excl + a0;
    }
    __syncthreads();

    const int cnt_b = min(bucket_fill[b], CAP);
    const int row0  = pref[b];
    const unsigned int* sb = scratch + (size_t)b * CAP;

    if (b == 0 && t == 0) row_start[n_nodes] = n_edges;

    if (t < 128) lhist[t] = 0;
    __syncthreads();

    for (int i = t; i < cnt_b; i += 256) {
        unsigned int u = sb[i];
        ent[i] = u;
        atomicAdd(&lhist[(u >> 16) & (BUCK_NODES - 1)], 1);
    }
    __syncthreads();

    int v = (t < 128) ? lhist[t] : 0;
    int x = v;
    stmp[t] = x;
    __syncthreads();
    for (int off = 1; off < 128; off <<= 1) {
        int y = (t >= off) ? stmp[t - off] : 0;
        __syncthreads();
        x += y;
        stmp[t] = x;
        __syncthreads();
    }
    if (t < 128) {
        int excl = x - v;
        lcur[t] = excl;
        int node = b * BUCK_NODES + t;
        if (node < n_nodes) {
            row_start[node] = row0 + excl;
            // degree histogram for the permutation (descending bins)
            atomicAdd(&deg_hist[DBINS - 1 - min(v, DBINS - 1)], 1);
        }
    }
    __syncthreads();

    for (int i = t; i < cnt_b; i += 256) {
        unsigned int u = ent[i];
        int dl = (u >> 16) & (BUCK_NODES - 1);
        int sv = (int)(u & 0xFFFFu);
        int r = atomicAdd(&lcur[dl], 1);
        int pos = row0 + r;
        sorted_src[pos] = sv;

        int node = b * BUCK_NODES + dl;
        float4 ss = *(const float4*)&s_src[sv * N_HEADS];
        float4 sd = *(const float4*)&s_dst[node * N_HEADS];
        float e0 = ss.x + sd.x; e0 = fmaxf(e0, NEG_SLOPE * e0);
        float e1 = ss.y + sd.y; e1 = fmaxf(e1, NEG_SLOPE * e1);
        float e2 = ss.z + sd.z; e2 = fmaxf(e2, NEG_SLOPE * e2);
        float e3 = ss.w + sd.w; e3 = fmaxf(e3, NEG_SLOPE * e3);
        uint2 pw;
        pw.x = pack_bf2(__expf(e0), __expf(e1));
        pw.y = pack_bf2(__expf(e2), __expf(e3));
        packed_ex[pos] = pw;
    }
}

// ---------------------------------------------------------------------------
// node permutation: counting sort by degree (descending bins). Adjacent
// perm entries have equal/similar degree -> wave-uniform gather loops.
// ---------------------------------------------------------------------------
__global__ __launch_bounds__(256) void perm_kernel(
    const int* __restrict__ row_start, const int* __restrict__ deg_hist,
    int* __restrict__ dfill, int* __restrict__ perm, int n_nodes)
{
    __shared__ int pref[DBINS];
    __shared__ int stmp[DBINS];

    int t = threadIdx.x;
    int v0 = (t < DBINS) ? deg_hist[t] : 0;
    int x = v0;
    if (t < DBINS) stmp[t] = x;
    __syncthreads();
    for (int off = 1; off < DBINS; off <<= 1) {
        int y = (t >= off && t < DBINS) ? stmp[t - off] : 0;
        __syncthreads();
        if (t < DBINS) { x += y; stmp[t] = x; }
        __syncthreads();
    }
    if (t < DBINS) pref[t] = x - v0;
    __syncthreads();

    int i = blockIdx.x * 256 + t;
    if (i < n_nodes) {
        int deg = row_start[i + 1] - row_start[i];
        int bin = DBINS - 1 - min(deg, DBINS - 1);
        int pos = pref[bin] + atomicAdd(&dfill[bin], 1);
        perm[pos] = i;
    }
}

// ---------------------------------------------------------------------------
// fused aggregate: TWO (similar-degree) nodes per wave via perm.
// Per node: 2 edge slots x 4-deep unroll = 8 edges in flight. Softmax
// numerators precomputed (bf16 pairs) -> no exp/score-gather here.
// ---------------------------------------------------------------------------
__global__ __launch_bounds__(256) void gather_kernel(
    const int* __restrict__ perm,
    const int* __restrict__ sorted_src, const int* __restrict__ row_start,
    const unsigned int* __restrict__ packed_ex,
    const unsigned int* __restrict__ zb,
    float* __restrict__ out, int n_nodes)
{
    int wave = (blockIdx.x * 256 + threadIdx.x) >> 6;
    int lane = threadIdx.x & 63;
    int half = lane >> 5;
    int pidx = wave * 2 + half;
    int g2   = (lane >> 4) & 1;      // edge slot 0..1
    int q    = lane & 15;            // col group: cols 8q..8q+7
    int hh   = q >> 2;               // head
    int exsel = hh >> 1;             // which word of the uint2
    bool exhi = (hh & 1);            // which bf16 half

    const bool valid = (pidx < n_nodes);
    const int node = perm[min(pidx, n_nodes - 1)];
    const int b0 = row_start[node];
    int deg = row_start[node + 1] - b0;
    if (!valid) deg = 0;

    f32x2 acc2[4];
    #pragma unroll
    for (int i = 0; i < 4; ++i) acc2[i] = (f32x2){0.f, 0.f};
    float den = 0.0f;

    if (deg > 0) {
        const int* sp = sorted_src + b0;
        const unsigned int* pex = packed_ex + (size_t)b0 * 2 + exsel;
        const int dm1 = deg - 1;

        for (int p = 0; p < deg; p += 8) {
            int i0 = p + g2, i1 = p + 2 + g2, i2 = p + 4 + g2, i3 = p + 6 + g2;
            int c0 = min(i0, dm1), c1 = min(i1, dm1);
            int c2 = min(i2, dm1), c3 = min(i3, dm1);
            int s0 = sp[c0];
            int s1 = sp[c1];
            int s2 = sp[c2];
            int s3 = sp[c3];
            unsigned int w0 = pex[c0 * 2];
            unsigned int w1 = pex[c1 * 2];
            unsigned int w2 = pex[c2 * 2];
            unsigned int w3 = pex[c3 * 2];
            uint4 u0 = *(const uint4*)&zb[(size_t)s0 * 64 + q * 4];
            uint4 u1 = *(const uint4*)&zb[(size_t)s1 * 64 + q * 4];
            uint4 u2 = *(const uint4*)&zb[(size_t)s2 * 64 + q * 4];
            uint4 u3 = *(const uint4*)&zb[(size_t)s3 * 64 + q * 4];

            float x0 = exhi ? bf_hi(w0) : bf_lo(w0);
            float x1 = exhi ? bf_hi(w1) : bf_lo(w1);
            float x2 = exhi ? bf_hi(w2) : bf_lo(w2);
            float x3 = exhi ? bf_hi(w3) : bf_lo(w3);
            if (i0 > dm1) x0 = 0.0f;
            if (i1 > dm1) x1 = 0.0f;
            if (i2 > dm1) x2 = 0.0f;
            if (i3 > dm1) x3 = 0.0f;
            den += (x0 + x1) + (x2 + x3);

            f32x2 xv;
            xv = (f32x2){x0, x0};
            acc2[0] += xv * bfpair(u0.x);
            acc2[1] += xv * bfpair(u0.y);
            acc2[2] += xv * bfpair(u0.z);
            acc2[3] += xv * bfpair(u0.w);
            xv = (f32x2){x1, x1};
            acc2[0] += xv * bfpair(u1.x);
            acc2[1] += xv * bfpair(u1.y);
            acc2[2] += xv * bfpair(u1.z);
            acc2[3] += xv * bfpair(u1.w);
            xv = (f32x2){x2, x2};
            acc2[0] += xv * bfpair(u2.x);
            acc2[1] += xv * bfpair(u2.y);
            acc2[2] += xv * bfpair(u2.z);
            acc2[3] += xv * bfpair(u2.w);
            xv = (f32x2){x3, x3};
            acc2[0] += xv * bfpair(u3.x);
            acc2[1] += xv * bfpair(u3.y);
            acc2[2] += xv * bfpair(u3.z);
            acc2[3] += xv * bfpair(u3.w);
        }
    }

    // reduce across the 2 edge slots (lane bit 4; stays within 32-lane half)
    #pragma unroll
    for (int i = 0; i < 4; ++i) {
        acc2[i].x += __shfl_xor(acc2[i].x, 16);
        acc2[i].y += __shfl_xor(acc2[i].y, 16);
    }
    den += __shfl_xor(den, 16);

    if (g2 == 0 && valid) {
        float inv = (deg > 0) ? 1.0f / den : 0.0f;
        float4 v0 = make_float4(acc2[0].x * inv, acc2[0].y * inv, acc2[1].x * inv, acc2[1].y * inv);
        float4 v1 = make_float4(acc2[2].x * inv, acc2[2].y * inv, acc2[3].x * inv, acc2[3].y * inv);
        float4* op = (float4*)&out[(size_t)node * OUT_DIM + q * 8];
        op[0] = v0;
        op[1] = v1;
    }
}

// ---------------------------------------------------------------------------
extern "C" void kernel_launch(void* const* d_in, const int* in_sizes, int n_in,
                              void* d_out, int out_size, void* d_ws, size_t ws_size,
                              hipStream_t stream)
{
    const float* h      = (const float*)d_in[0];
    const float* fc_w   = (const float*)d_in[1];
    const float* attn_w = (const float*)d_in[2];
    const int*   src    = (const int*)d_in[3];
    const int*   dst    = (const int*)d_in[4];

    const int n_nodes = in_sizes[0] / IN_DIM;   // 50000
    const int n_edges = in_sizes[3];            // 800000
    const int nbuck   = (n_nodes + BUCK_NODES - 1) / BUCK_NODES;   // 391

    float* out = (float*)d_out;

    // workspace layout (4-byte units; packed_ex needs 8B alignment)
    char* ws = (char*)d_ws;
    unsigned int* zb      = (unsigned int*)ws;                          // n_nodes*64 u32
    float* s_src          = (float*)(zb + (size_t)n_nodes * 64);        // n_nodes*4
    float* s_dst          = s_src + (size_t)n_nodes * N_HEADS;          // n_nodes*4
    int*   row_start      = (int*)(s_dst + (size_t)n_nodes * N_HEADS);  // n_nodes+1 (+pad)
    int*   bucket_fill    = row_start + n_nodes + 16;                   // nbuck
    int*   deg_hist       = bucket_fill + nbuck + 16;                   // DBINS
    int*   dfill          = deg_hist + DBINS;                           // DBINS
    int*   perm           = dfill + DBINS;                              // n_nodes
    int*   sorted_src     = perm + n_nodes + 16;                        // n_edges
    uint2* packed_ex      = (uint2*)(sorted_src + n_edges + 16);        // n_edges uint2
    unsigned int* scratch = (unsigned int*)(packed_ex + n_edges);       // nbuck*CAP
    unsigned short* wl_g  = (unsigned short*)(scratch + (size_t)nbuck * CAP); // 32768 bf16

    // 1. setup: W prep + zero counters
    setup_kernel<<<128, 256, 0, stream>>>(fc_w, wl_g, bucket_fill, nbuck, deg_hist);

    // 2. bucket pass A (dst-bucket scatter, dense writes)
    bucketA_kernel<<<(n_edges + CHUNK - 1) / CHUNK, 256, 0, stream>>>(
        src, dst, bucket_fill, scratch, n_edges, nbuck);

    // 3. dense phase: MFMA GEMM (fused scores + bf16 z), 256 rows/block
    gemm_mfma_kernel<<<(n_nodes + 255) / 256, 512, 0, stream>>>(
        h, wl_g, attn_w, zb, s_src, s_dst, n_nodes);

    // 4. bucket pass B: CSR finalize + per-(edge,head) softmax numerators
    bucketB_kernel<<<nbuck, 256, 0, stream>>>(
        scratch, bucket_fill, s_src, s_dst,
        row_start, sorted_src, packed_ex, deg_hist, n_nodes, nbuck, n_edges);

    // 5. degree-sorted node permutation
    perm_kernel<<<(n_nodes + 255) / 256, 256, 0, stream>>>(
        row_start, deg_hist, dfill, perm, n_nodes);

    // 6. fused aggregate, 2 similar-degree nodes per wave
    {
        int waves = (n_nodes + 1) / 2;
        int blocks = (waves * 64 + 255) / 256;
        gather_kernel<<<blocks, 256, 0, stream>>>(
            perm, sorted_src, row_start, (const unsigned int*)packed_ex, zb, out, n_nodes);
    }
}

// Round 12
// 384.940 us; speedup vs baseline: 1.0073x; 1.0073x over previous
//
#include <hip/hip_runtime.h>
#include <hip/hip_bf16.h>
#include <math.h>

#define N_HEADS 4
#define D_HEAD 32
#define IN_DIM 256
#define OUT_DIM (N_HEADS * D_HEAD)   // 128
#define NEG_SLOPE 0.01f

// CSR-build geometry: 128 nodes per bucket, padded scratch regions.
// NOTE: packing (dst<<16 | src) requires n_nodes < 65536 (here 50000).
#define BSHIFT 7
#define BUCK_NODES 128
#define CAP 4096            // scratch slots per bucket (avg fill ~2048)
#define CHUNK 8192          // edges per pass-A block
#define DBINS 64            // degree bins for node permutation

typedef __attribute__((ext_vector_type(8))) short bf16x8;
typedef __attribute__((ext_vector_type(4))) float f32x4;
typedef __attribute__((ext_vector_type(2))) float f32x2;

// round-to-nearest-even f32 -> bf16 (as u16) — cold path only (setup)
static __device__ __forceinline__ unsigned short f2bf(float x)
{
    unsigned int u = __float_as_uint(x);
    u = u + 0x7FFFu + ((u >> 16) & 1u);
    return (unsigned short)(u >> 16);
}

// hot-path pack: 2 floats -> packed bf16x2 (v_cvt_pk_bf16_f32)
static __device__ __forceinline__ unsigned int pack_bf2(float a, float b)
{
    union { __hip_bfloat162 b2; unsigned int u; } r;
    r.b2 = __float22bfloat162_rn(make_float2(a, b));
    return r.u;
}

static __device__ __forceinline__ float bf_lo(unsigned int u)
{
    return __uint_as_float(u << 16);
}
static __device__ __forceinline__ float bf_hi(unsigned int u)
{
    return __uint_as_float(u & 0xFFFF0000u);
}

static __device__ __forceinline__ f32x2 bfpair(unsigned int u)
{
    f32x2 r;
    r.x = bf_lo(u);
    r.y = bf_hi(u);
    return r;
}

// ---------------------------------------------------------------------------
// setup: arrange fc_w into MFMA-B-fragment order (bf16); zero bucket_fill,
// deg_hist, dfill.
// ---------------------------------------------------------------------------
__global__ void setup_kernel(const float* __restrict__ fc_w,
                             unsigned short* __restrict__ wl,
                             int* __restrict__ bucket_fill, int nbuck,
                             int* __restrict__ deg_zero /* deg_hist+dfill, 2*DBINS */)
{
    int o = blockIdx.x * blockDim.x + threadIdx.x;   // 0..32767
    if (o < nbuck) bucket_fill[o] = 0;
    if (o < 2 * DBINS) deg_zero[o] = 0;
    if (o >= 32768) return;
    int j  = o & 7;
    int l  = (o >> 3) & 63;
    int kf = (o >> 9) & 7;
    int cf = (o >> 12) & 7;
    int k   = kf * 32 + (l >> 4) * 8 + j;
    int col = cf * 16 + (l & 15);
    int hh = col >> 5, d = col & 31;
    wl[o] = f2bf(fc_w[hh * 8192 + k * 32 + d]);
}

// ---------------------------------------------------------------------------
// MFMA GEMM: 256 rows/block, 8 waves x 32 rows (2 fragment sets per wave).
// ---------------------------------------------------------------------------
__global__ __launch_bounds__(512, 4) void gemm_mfma_kernel(
    const float* __restrict__ h, const unsigned short* __restrict__ wl,
    const float* __restrict__ attn_w,
    unsigned int* __restrict__ zb,
    float* __restrict__ s_src, float* __restrict__ s_dst,
    int n_nodes)
{
    __shared__ unsigned short wls[32768];   // 64 KB

    const int t = threadIdx.x;

    #pragma unroll
    for (int it = 0; it < 8; ++it) {
        ((uint4*)wls)[t + it * 512] = ((const uint4*)wl)[t + it * 512];
    }
    __syncthreads();

    const int w  = t >> 6;          // wave 0..7
    const int l  = t & 63;
    const int g  = l >> 4;
    const int ln = l & 15;
    const int m0 = blockIdx.x * 256 + w * 32;

    const int arowA = min(m0 + ln,      n_nodes - 1);
    const int arowB = min(m0 + 16 + ln, n_nodes - 1);
    const float4* hrowA = (const float4*)(h + (size_t)arowA * IN_DIM);
    const float4* hrowB = (const float4*)(h + (size_t)arowB * IN_DIM);

    f32x4 accA[8], accB[8];
    #pragma unroll
    for (int cf = 0; cf < 8; ++cf) {
        accA[cf] = (f32x4){0.f, 0.f, 0.f, 0.f};
        accB[cf] = (f32x4){0.f, 0.f, 0.f, 0.f};
    }

    #pragma unroll
    for (int kf = 0; kf < 8; ++kf) {
        float4 a0 = hrowA[kf * 8 + g * 2];
        float4 a1 = hrowA[kf * 8 + g * 2 + 1];
        float4 b0 = hrowB[kf * 8 + g * 2];
        float4 b1 = hrowB[kf * 8 + g * 2 + 1];
        union { unsigned int u[4]; bf16x8 v; } faA, faB;
        faA.u[0] = pack_bf2(a0.x, a0.y);
        faA.u[1] = pack_bf2(a0.z, a0.w);
        faA.u[2] = pack_bf2(a1.x, a1.y);
        faA.u[3] = pack_bf2(a1.z, a1.w);
        faB.u[0] = pack_bf2(b0.x, b0.y);
        faB.u[1] = pack_bf2(b0.z, b0.w);
        faB.u[2] = pack_bf2(b1.x, b1.y);
        faB.u[3] = pack_bf2(b1.z, b1.w);

        #pragma unroll
        for (int cf = 0; cf < 8; ++cf) {
            bf16x8 fb = *(const bf16x8*)&wls[((cf * 8 + kf) * 64 + l) * 8];
            accA[cf] = __builtin_amdgcn_mfma_f32_16x16x32_bf16(faA.v, fb, accA[cf], 0, 0, 0);
            accB[cf] = __builtin_amdgcn_mfma_f32_16x16x32_bf16(faB.v, fb, accB[cf], 0, 0, 0);
        }
    }

    float aw_s[8], aw_d[8];
    #pragma unroll
    for (int cf = 0; cf < 8; ++cf) {
        int col = cf * 16 + ln;
        int hh = col >> 5, d = col & 31;
        aw_s[cf] = attn_w[hh * 64 + d];
        aw_d[cf] = attn_w[hh * 64 + 32 + d];
    }

    #pragma unroll
    for (int set = 0; set < 2; ++set) {
        const int rb = m0 + set * 16;
        #pragma unroll
        for (int r = 0; r < 4; ++r) {
            const int row = rb + 4 * g + r;
            const bool ok = (row < n_nodes);
            f32x4* acc = set ? accB : accA;

            float vs0 = acc[0][r] * aw_s[0] + acc[1][r] * aw_s[1];
            float vs1 = acc[2][r] * aw_s[2] + acc[3][r] * aw_s[3];
            float vs2 = acc[4][r] * aw_s[4] + acc[5][r] * aw_s[5];
            float vs3 = acc[6][r] * aw_s[6] + acc[7][r] * aw_s[7];
            float vd0 = acc[0][r] * aw_d[0] + acc[1][r] * aw_d[1];
            float vd1 = acc[2][r] * aw_d[2] + acc[3][r] * aw_d[3];
            float vd2 = acc[4][r] * aw_d[4] + acc[5][r] * aw_d[5];
            float vd3 = acc[6][r] * aw_d[6] + acc[7][r] * aw_d[7];
            #pragma unroll
            for (int mk = 1; mk < 16; mk <<= 1) {
                vs0 += __shfl_xor(vs0, mk); vs1 += __shfl_xor(vs1, mk);
                vs2 += __shfl_xor(vs2, mk); vs3 += __shfl_xor(vs3, mk);
                vd0 += __shfl_xor(vd0, mk); vd1 += __shfl_xor(vd1, mk);
                vd2 += __shfl_xor(vd2, mk); vd3 += __shfl_xor(vd3, mk);
            }
            float sel_s = (ln == 0) ? vs0 : (ln == 1) ? vs1 : (ln == 2) ? vs2 : vs3;
            float sel_d = ((ln & 3) == 0) ? vd0 : ((ln & 3) == 1) ? vd1 : ((ln & 3) == 2) ? vd2 : vd3;
            if (ok && ln < 4)              s_src[row * N_HEADS + ln]       = sel_s;
            if (ok && ln >= 4 && ln < 8)   s_dst[row * N_HEADS + (ln & 3)] = sel_d;

            #pragma unroll
            for (int cf = 0; cf < 8; ++cf) {
                float v = acc[cf][r];
                float o = __shfl_xor(v, 1);
                if (!(ln & 1) && ok) {
                    zb[(size_t)row * 64 + cf * 8 + (ln >> 1)] = pack_bf2(v, o);
                }
            }
        }
    }
}

// ---------------------------------------------------------------------------
// Pass A: bucket-scatter with LDS aggregation (dense scratch writes).
// ---------------------------------------------------------------------------
__global__ __launch_bounds__(256) void bucketA_kernel(
    const int* __restrict__ src, const int* __restrict__ dst,
    int* __restrict__ bucket_fill, unsigned int* __restrict__ scratch,
    int n_edges, int nbuck)
{
    __shared__ int bhist[512];
    __shared__ int boff[512];
    __shared__ int goff[512];
    __shared__ int bcur[512];
    __shared__ int stmp[256];
    __shared__ unsigned int lpair[CHUNK];   // 32 KB

    const int t  = threadIdx.x;
    const int e0 = blockIdx.x * CHUNK;
    const int n  = min(CHUNK, n_edges - e0);

    bhist[t] = 0; bhist[t + 256] = 0;
    __syncthreads();

    for (int i = t; i < n; i += 256) {
        atomicAdd(&bhist[dst[e0 + i] >> BSHIFT], 1);
    }
    __syncthreads();

    int a0 = bhist[2 * t], a1 = bhist[2 * t + 1];
    int s  = a0 + a1;
    int x  = s;
    stmp[t] = x;
    __syncthreads();
    for (int off = 1; off < 256; off <<= 1) {
        int y = (t >= off) ? stmp[t - off] : 0;
        __syncthreads();
        x += y;
        stmp[t] = x;
        __syncthreads();
    }
    int excl = x - s;
    boff[2 * t]     = excl;
    boff[2 * t + 1] = excl + a0;
    bcur[2 * t]     = excl;
    bcur[2 * t + 1] = excl + a0;

    #pragma unroll
    for (int b = t; b < 512; b += 256) {
        int c = bhist[b];
        goff[b] = (c > 0) ? (b * CAP + atomicAdd(&bucket_fill[b], c)) : 0;
    }
    __syncthreads();

    for (int i = t; i < n; i += 256) {
        int d  = dst[e0 + i];
        int sv = src[e0 + i];
        int p  = atomicAdd(&bcur[d >> BSHIFT], 1);
        lpair[p] = ((unsigned int)d << 16) | (unsigned int)sv;
    }
    __syncthreads();

    const int lim = nbuck * CAP - 1;
    for (int i = t; i < n; i += 256) {
        unsigned int u = lpair[i];
        int b = (int)(u >> 16) >> BSHIFT;
        int addr = goff[b] + (i - boff[b]);
        scratch[min(addr, lim)] = u;
    }
}

// ---------------------------------------------------------------------------
// Pass B: one block per bucket, PURE LDS work + dense writes (round-10 form).
// Redundant bucket scan -> row0; per-node LDS histogram + scan -> row_start
// + deg_hist; placement writes the full packed (dst<<16|src) word.
// ---------------------------------------------------------------------------
__global__ __launch_bounds__(256) void bucketB_kernel(
    const unsigned int* __restrict__ scratch,
    const int* __restrict__ bucket_fill,
    int* __restrict__ row_start,
    unsigned int* __restrict__ sorted_pair,
    int* __restrict__ deg_hist,
    int n_nodes, int nbuck, int n_edges)
{
    __shared__ int pref[512];
    __shared__ int lhist[128];
    __shared__ int lcur[128];
    __shared__ int stmp[256];
    __shared__ unsigned int ent[CAP];   // 16 KB

    const int b = blockIdx.x;
    const int t = threadIdx.x;

    // --- redundant exclusive scan of bucket_fill -> pref[] ---
    {
        int a0 = (2 * t     < nbuck) ? min(bucket_fill[2 * t],     CAP) : 0;
        int a1 = (2 * t + 1 < nbuck) ? min(bucket_fill[2 * t + 1], CAP) : 0;
        int s = a0 + a1;
        int x = s;
        stmp[t] = x;
        __syncthreads();
        for (int off = 1; off < 256; off <<= 1) {
            int y = (t >= off) ? stmp[t - off] : 0;
            __syncthreads();
            x += y;
            stmp[t] = x;
            __syncthreads();
        }
        int excl = x - s;
        pref[2 * t]     = excl;
        pref[2 * t + 1] = excl + a0;
    }
    __syncthreads();

    const int cnt_b = min(bucket_fill[b], CAP);
    const int row0  = pref[b];
    const unsigned int* sb = scratch + (size_t)b * CAP;

    if (b == 0 && t == 0) row_start[n_nodes] = n_edges;

    if (t < 128) lhist[t] = 0;
    __syncthreads();

    for (int i = t; i < cnt_b; i += 256) {
        unsigned int u = sb[i];
        ent[i] = u;
        atomicAdd(&lhist[(u >> 16) & (BUCK_NODES - 1)], 1);
    }
    __syncthreads();

    int v = (t < 128) ? lhist[t] : 0;
    int x = v;
    stmp[t] = x;
    __syncthreads();
    for (int off = 1; off < 128; off <<= 1) {
        int y = (t >= off) ? stmp[t - off] : 0;
        __syncthreads();
        x += y;
        stmp[t] = x;
        __syncthreads();
    }
    if (t < 128) {
        int excl = x - v;
        lcur[t] = excl;
        int node = b * BUCK_NODES + t;
        if (node < n_nodes) {
            row_start[node] = row0 + excl;
            atomicAdd(&deg_hist[DBINS - 1 - min(v, DBINS - 1)], 1);
        }
    }
    __syncthreads();

    for (int i = t; i < cnt_b; i += 256) {
        unsigned int u = ent[i];
        int dl = (u >> 16) & (BUCK_NODES - 1);
        int r = atomicAdd(&lcur[dl], 1);
        sorted_pair[row0 + r] = u;
    }
}

// ---------------------------------------------------------------------------
// flat per-edge kernel (full TLP): reads sorted_pair densely, gathers
// per-node scores, computes bf16 softmax numerators for all 4 heads,
// writes packed_ex densely and rewrites sorted_pair -> plain src in place.
// ---------------------------------------------------------------------------
__global__ __launch_bounds__(256) void ex_kernel(
    unsigned int* __restrict__ sorted_pair,
    const float* __restrict__ s_src, const float* __restrict__ s_dst,
    uint2* __restrict__ packed_ex, int n_edges)
{
    int i = blockIdx.x * 256 + threadIdx.x;
    if (i >= n_edges) return;
    unsigned int u = sorted_pair[i];
    int sv = (int)(u & 0xFFFFu);
    int dn = (int)(u >> 16);
    float4 ss = *(const float4*)&s_src[sv * N_HEADS];
    float4 sd = *(const float4*)&s_dst[dn * N_HEADS];
    float e0 = ss.x + sd.x; e0 = fmaxf(e0, NEG_SLOPE * e0);
    float e1 = ss.y + sd.y; e1 = fmaxf(e1, NEG_SLOPE * e1);
    float e2 = ss.z + sd.z; e2 = fmaxf(e2, NEG_SLOPE * e2);
    float e3 = ss.w + sd.w; e3 = fmaxf(e3, NEG_SLOPE * e3);
    uint2 pw;
    pw.x = pack_bf2(__expf(e0), __expf(e1));
    pw.y = pack_bf2(__expf(e2), __expf(e3));
    packed_ex[i] = pw;
    sorted_pair[i] = (unsigned int)sv;
}

// ---------------------------------------------------------------------------
// node permutation: counting sort by degree (descending bins).
// ---------------------------------------------------------------------------
__global__ __launch_bounds__(256) void perm_kernel(
    const int* __restrict__ row_start, const int* __restrict__ deg_hist,
    int* __restrict__ dfill, int* __restrict__ perm, int n_nodes)
{
    __shared__ int pref[DBINS];
    __shared__ int stmp[DBINS];

    int t = threadIdx.x;
    int v0 = (t < DBINS) ? deg_hist[t] : 0;
    int x = v0;
    if (t < DBINS) stmp[t] = x;
    __syncthreads();
    for (int off = 1; off < DBINS; off <<= 1) {
        int y = (t >= off && t < DBINS) ? stmp[t - off] : 0;
        __syncthreads();
        if (t < DBINS) { x += y; stmp[t] = x; }
        __syncthreads();
    }
    if (t < DBINS) pref[t] = x - v0;
    __syncthreads();

    int i = blockIdx.x * 256 + t;
    if (i < n_nodes) {
        int deg = row_start[i + 1] - row_start[i];
        int bin = DBINS - 1 - min(deg, DBINS - 1);
        int pos = pref[bin] + atomicAdd(&dfill[bin], 1);
        perm[pos] = i;
    }
}

// ---------------------------------------------------------------------------
// fused aggregate: TWO (similar-degree) nodes per wave via perm.
// Per node: 2 edge slots x 4-deep unroll = 8 edges in flight. Softmax
// numerators precomputed (bf16 pairs) -> no exp/score-gather here.
// ---------------------------------------------------------------------------
__global__ __launch_bounds__(256) void gather_kernel(
    const int* __restrict__ perm,
    const int* __restrict__ sorted_src, const int* __restrict__ row_start,
    const unsigned int* __restrict__ packed_ex,
    const unsigned int* __restrict__ zb,
    float* __restrict__ out, int n_nodes)
{
    int wave = (blockIdx.x * 256 + threadIdx.x) >> 6;
    int lane = threadIdx.x & 63;
    int half = lane >> 5;
    int pidx = wave * 2 + half;
    int g2   = (lane >> 4) & 1;      // edge slot 0..1
    int q    = lane & 15;            // col group: cols 8q..8q+7
    int hh   = q >> 2;               // head
    int exsel = hh >> 1;             // which word of the uint2
    bool exhi = (hh & 1);            // which bf16 half

    const bool valid = (pidx < n_nodes);
    const int node = perm[min(pidx, n_nodes - 1)];
    const int b0 = row_start[node];
    int deg = row_start[node + 1] - b0;
    if (!valid) deg = 0;

    f32x2 acc2[4];
    #pragma unroll
    for (int i = 0; i < 4; ++i) acc2[i] = (f32x2){0.f, 0.f};
    float den = 0.0f;

    if (deg > 0) {
        const int* sp = sorted_src + b0;
        const unsigned int* pex = packed_ex + (size_t)b0 * 2 + exsel;
        const int dm1 = deg - 1;

        for (int p = 0; p < deg; p += 8) {
            int i0 = p + g2, i1 = p + 2 + g2, i2 = p + 4 + g2, i3 = p + 6 + g2;
            int c0 = min(i0, dm1), c1 = min(i1, dm1);
            int c2 = min(i2, dm1), c3 = min(i3, dm1);
            int s0 = sp[c0];
            int s1 = sp[c1];
            int s2 = sp[c2];
            int s3 = sp[c3];
            unsigned int w0 = pex[c0 * 2];
            unsigned int w1 = pex[c1 * 2];
            unsigned int w2 = pex[c2 * 2];
            unsigned int w3 = pex[c3 * 2];
            uint4 u0 = *(const uint4*)&zb[(size_t)s0 * 64 + q * 4];
            uint4 u1 = *(const uint4*)&zb[(size_t)s1 * 64 + q * 4];
            uint4 u2 = *(const uint4*)&zb[(size_t)s2 * 64 + q * 4];
            uint4 u3 = *(const uint4*)&zb[(size_t)s3 * 64 + q * 4];

            float x0 = exhi ? bf_hi(w0) : bf_lo(w0);
            float x1 = exhi ? bf_hi(w1) : bf_lo(w1);
            float x2 = exhi ? bf_hi(w2) : bf_lo(w2);
            float x3 = exhi ? bf_hi(w3) : bf_lo(w3);
            if (i0 > dm1) x0 = 0.0f;
            if (i1 > dm1) x1 = 0.0f;
            if (i2 > dm1) x2 = 0.0f;
            if (i3 > dm1) x3 = 0.0f;
            den += (x0 + x1) + (x2 + x3);

            f32x2 xv;
            xv = (f32x2){x0, x0};
            acc2[0] += xv * bfpair(u0.x);
            acc2[1] += xv * bfpair(u0.y);
            acc2[2] += xv * bfpair(u0.z);
            acc2[3] += xv * bfpair(u0.w);
            xv = (f32x2){x1, x1};
            acc2[0] += xv * bfpair(u1.x);
            acc2[1] += xv * bfpair(u1.y);
            acc2[2] += xv * bfpair(u1.z);
            acc2[3] += xv * bfpair(u1.w);
            xv = (f32x2){x2, x2};
            acc2[0] += xv * bfpair(u2.x);
            acc2[1] += xv * bfpair(u2.y);
            acc2[2] += xv * bfpair(u2.z);
            acc2[3] += xv * bfpair(u2.w);
            xv = (f32x2){x3, x3};
            acc2[0] += xv * bfpair(u3.x);
            acc2[1] += xv * bfpair(u3.y);
            acc2[2] += xv * bfpair(u3.z);
            acc2[3] += xv * bfpair(u3.w);
        }
    }

    #pragma unroll
    for (int i = 0; i < 4; ++i) {
        acc2[i].x += __shfl_xor(acc2[i].x, 16);
        acc2[i].y += __shfl_xor(acc2[i].y, 16);
    }
    den += __shfl_xor(den, 16);

    if (g2 == 0 && valid) {
        float inv = (deg > 0) ? 1.0f / den : 0.0f;
        float4 v0 = make_float4(acc2[0].x * inv, acc2[0].y * inv, acc2[1].x * inv, acc2[1].y * inv);
        float4 v1 = make_float4(acc2[2].x * inv, acc2[2].y * inv, acc2[3].x * inv, acc2[3].y * inv);
        float4* op = (float4*)&out[(size_t)node * OUT_DIM + q * 8];
        op[0] = v0;
        op[1] = v1;
    }
}

// ---------------------------------------------------------------------------
extern "C" void kernel_launch(void* const* d_in, const int* in_sizes, int n_in,
                              void* d_out, int out_size, void* d_ws, size_t ws_size,
                              hipStream_t stream)
{
    const float* h      = (const float*)d_in[0];
    const float* fc_w   = (const float*)d_in[1];
    const float* attn_w = (const float*)d_in[2];
    const int*   src    = (const int*)d_in[3];
    const int*   dst    = (const int*)d_in[4];

    const int n_nodes = in_sizes[0] / IN_DIM;   // 50000
    const int n_edges = in_sizes[3];            // 800000
    const int nbuck   = (n_nodes + BUCK_NODES - 1) / BUCK_NODES;   // 391

    float* out = (float*)d_out;

    // workspace layout (4-byte units; packed_ex needs 8B alignment)
    char* ws = (char*)d_ws;
    unsigned int* zb      = (unsigned int*)ws;                          // n_nodes*64 u32
    float* s_src          = (float*)(zb + (size_t)n_nodes * 64);        // n_nodes*4
    float* s_dst          = s_src + (size_t)n_nodes * N_HEADS;          // n_nodes*4
    int*   row_start      = (int*)(s_dst + (size_t)n_nodes * N_HEADS);  // n_nodes+1 (+pad)
    int*   bucket_fill    = row_start + n_nodes + 16;                   // nbuck
    int*   deg_hist       = bucket_fill + nbuck + 16;                   // DBINS
    int*   dfill          = deg_hist + DBINS;                           // DBINS
    int*   perm           = dfill + DBINS;                              // n_nodes
    unsigned int* sorted_pair = (unsigned int*)(perm + n_nodes + 16);   // n_edges (becomes sorted_src)
    uint2* packed_ex      = (uint2*)(sorted_pair + n_edges + 16);       // n_edges uint2
    unsigned int* scratch = (unsigned int*)(packed_ex + n_edges);       // nbuck*CAP
    unsigned short* wl_g  = (unsigned short*)(scratch + (size_t)nbuck * CAP); // 32768 bf16

    // 1. setup: W prep + zero counters
    setup_kernel<<<128, 256, 0, stream>>>(fc_w, wl_g, bucket_fill, nbuck, deg_hist);

    // 2. bucket pass A (dst-bucket scatter, dense writes)
    bucketA_kernel<<<(n_edges + CHUNK - 1) / CHUNK, 256, 0, stream>>>(
        src, dst, bucket_fill, scratch, n_edges, nbuck);

    // 3. bucket pass B: CSR finalize (pure LDS + dense writes)
    bucketB_kernel<<<nbuck, 256, 0, stream>>>(
        scratch, bucket_fill, row_start, sorted_pair, deg_hist,
        n_nodes, nbuck, n_edges);

    // 4. dense phase: MFMA GEMM (fused scores + bf16 z), 256 rows/block
    gemm_mfma_kernel<<<(n_nodes + 255) / 256, 512, 0, stream>>>(
        h, wl_g, attn_w, zb, s_src, s_dst, n_nodes);

    // 5. flat per-edge softmax numerators (full TLP)
    ex_kernel<<<(n_edges + 255) / 256, 256, 0, stream>>>(
        sorted_pair, s_src, s_dst, packed_ex, n_edges);

    // 6. degree-sorted node permutation
    perm_kernel<<<(n_nodes + 255) / 256, 256, 0, stream>>>(
        row_start, deg_hist, dfill, perm, n_nodes);

    // 7. fused aggregate, 2 similar-degree nodes per wave
    {
        int waves = (n_nodes + 1) / 2;
        int blocks = (waves * 64 + 255) / 256;
        gather_kernel<<<blocks, 256, 0, stream>>>(
            perm, (const int*)sorted_pair, row_start,
            (const unsigned int*)packed_ex, zb, out, n_nodes);
    }
}

// Round 13
// 97.232 us; speedup vs baseline: 3.9877x; 3.9590x over previous
//
#include <hip/hip_runtime.h>
#include <hip/hip_bf16.h>
#include <math.h>

#define N_HEADS 4
#define D_HEAD 32
#define IN_DIM 256
#define OUT_DIM (N_HEADS * D_HEAD)   // 128
#define NEG_SLOPE 0.01f

// CSR-build geometry: 128 nodes per bucket, padded scratch regions.
// NOTE: packing (dst<<16 | src) requires n_nodes < 65536 (here 50000).
#define BSHIFT 7
#define BUCK_NODES 128
#define CAP 4096            // scratch slots per bucket (avg fill ~2048)
#define CHUNK 8192          // edges per pass-A block

typedef __attribute__((ext_vector_type(8))) short bf16x8;
typedef __attribute__((ext_vector_type(4))) float f32x4;
typedef __attribute__((ext_vector_type(2))) float f32x2;

// round-to-nearest-even f32 -> bf16 (as u16) — cold path only (setup)
static __device__ __forceinline__ unsigned short f2bf(float x)
{
    unsigned int u = __float_as_uint(x);
    u = u + 0x7FFFu + ((u >> 16) & 1u);
    return (unsigned short)(u >> 16);
}

// hot-path pack: 2 floats -> packed bf16x2 (v_cvt_pk_bf16_f32)
static __device__ __forceinline__ unsigned int pack_bf2(float a, float b)
{
    union { __hip_bfloat162 b2; unsigned int u; } r;
    r.b2 = __float22bfloat162_rn(make_float2(a, b));
    return r.u;
}

static __device__ __forceinline__ float bf_lo(unsigned int u)
{
    return __uint_as_float(u << 16);
}
static __device__ __forceinline__ float bf_hi(unsigned int u)
{
    return __uint_as_float(u & 0xFFFF0000u);
}

static __device__ __forceinline__ f32x2 bfpair(unsigned int u)
{
    f32x2 r;
    r.x = bf_lo(u);
    r.y = bf_hi(u);
    return r;
}

// ---------------------------------------------------------------------------
// setup: arrange fc_w into MFMA-B-fragment order (bf16); zero bucket_fill.
// ---------------------------------------------------------------------------
__global__ void setup_kernel(const float* __restrict__ fc_w,
                             unsigned short* __restrict__ wl,
                             int* __restrict__ bucket_fill, int nbuck)
{
    int o = blockIdx.x * blockDim.x + threadIdx.x;   // 0..32767
    if (o < nbuck) bucket_fill[o] = 0;
    if (o >= 32768) return;
    int j  = o & 7;
    int l  = (o >> 3) & 63;
    int kf = (o >> 9) & 7;
    int cf = (o >> 12) & 7;
    int k   = kf * 32 + (l >> 4) * 8 + j;
    int col = cf * 16 + (l & 15);
    int hh = col >> 5, d = col & 31;
    wl[o] = f2bf(fc_w[hh * 8192 + k * 32 + d]);
}

// ---------------------------------------------------------------------------
// MFMA GEMM: 256 rows/block, 8 waves x 32 rows (2 fragment sets per wave).
// ---------------------------------------------------------------------------
__global__ __launch_bounds__(512, 4) void gemm_mfma_kernel(
    const float* __restrict__ h, const unsigned short* __restrict__ wl,
    const float* __restrict__ attn_w,
    unsigned int* __restrict__ zb,
    float* __restrict__ s_src, float* __restrict__ s_dst,
    int n_nodes)
{
    __shared__ unsigned short wls[32768];   // 64 KB

    const int t = threadIdx.x;

    #pragma unroll
    for (int it = 0; it < 8; ++it) {
        ((uint4*)wls)[t + it * 512] = ((const uint4*)wl)[t + it * 512];
    }
    __syncthreads();

    const int w  = t >> 6;          // wave 0..7
    const int l  = t & 63;
    const int g  = l >> 4;
    const int ln = l & 15;
    const int m0 = blockIdx.x * 256 + w * 32;

    const int arowA = min(m0 + ln,      n_nodes - 1);
    const int arowB = min(m0 + 16 + ln, n_nodes - 1);
    const float4* hrowA = (const float4*)(h + (size_t)arowA * IN_DIM);
    const float4* hrowB = (const float4*)(h + (size_t)arowB * IN_DIM);

    f32x4 accA[8], accB[8];
    #pragma unroll
    for (int cf = 0; cf < 8; ++cf) {
        accA[cf] = (f32x4){0.f, 0.f, 0.f, 0.f};
        accB[cf] = (f32x4){0.f, 0.f, 0.f, 0.f};
    }

    #pragma unroll
    for (int kf = 0; kf < 8; ++kf) {
        float4 a0 = hrowA[kf * 8 + g * 2];
        float4 a1 = hrowA[kf * 8 + g * 2 + 1];
        float4 b0 = hrowB[kf * 8 + g * 2];
        float4 b1 = hrowB[kf * 8 + g * 2 + 1];
        union { unsigned int u[4]; bf16x8 v; } faA, faB;
        faA.u[0] = pack_bf2(a0.x, a0.y);
        faA.u[1] = pack_bf2(a0.z, a0.w);
        faA.u[2] = pack_bf2(a1.x, a1.y);
        faA.u[3] = pack_bf2(a1.z, a1.w);
        faB.u[0] = pack_bf2(b0.x, b0.y);
        faB.u[1] = pack_bf2(b0.z, b0.w);
        faB.u[2] = pack_bf2(b1.x, b1.y);
        faB.u[3] = pack_bf2(b1.z, b1.w);

        #pragma unroll
        for (int cf = 0; cf < 8; ++cf) {
            bf16x8 fb = *(const bf16x8*)&wls[((cf * 8 + kf) * 64 + l) * 8];
            accA[cf] = __builtin_amdgcn_mfma_f32_16x16x32_bf16(faA.v, fb, accA[cf], 0, 0, 0);
            accB[cf] = __builtin_amdgcn_mfma_f32_16x16x32_bf16(faB.v, fb, accB[cf], 0, 0, 0);
        }
    }

    float aw_s[8], aw_d[8];
    #pragma unroll
    for (int cf = 0; cf < 8; ++cf) {
        int col = cf * 16 + ln;
        int hh = col >> 5, d = col & 31;
        aw_s[cf] = attn_w[hh * 64 + d];
        aw_d[cf] = attn_w[hh * 64 + 32 + d];
    }

    #pragma unroll
    for (int set = 0; set < 2; ++set) {
        const int rb = m0 + set * 16;
        #pragma unroll
        for (int r = 0; r < 4; ++r) {
            const int row = rb + 4 * g + r;
            const bool ok = (row < n_nodes);
            f32x4* acc = set ? accB : accA;

            float vs0 = acc[0][r] * aw_s[0] + acc[1][r] * aw_s[1];
            float vs1 = acc[2][r] * aw_s[2] + acc[3][r] * aw_s[3];
            float vs2 = acc[4][r] * aw_s[4] + acc[5][r] * aw_s[5];
            float vs3 = acc[6][r] * aw_s[6] + acc[7][r] * aw_s[7];
            float vd0 = acc[0][r] * aw_d[0] + acc[1][r] * aw_d[1];
            float vd1 = acc[2][r] * aw_d[2] + acc[3][r] * aw_d[3];
            float vd2 = acc[4][r] * aw_d[4] + acc[5][r] * aw_d[5];
            float vd3 = acc[6][r] * aw_d[6] + acc[7][r] * aw_d[7];
            #pragma unroll
            for (int mk = 1; mk < 16; mk <<= 1) {
                vs0 += __shfl_xor(vs0, mk); vs1 += __shfl_xor(vs1, mk);
                vs2 += __shfl_xor(vs2, mk); vs3 += __shfl_xor(vs3, mk);
                vd0 += __shfl_xor(vd0, mk); vd1 += __shfl_xor(vd1, mk);
                vd2 += __shfl_xor(vd2, mk); vd3 += __shfl_xor(vd3, mk);
            }
            float sel_s = (ln == 0) ? vs0 : (ln == 1) ? vs1 : (ln == 2) ? vs2 : vs3;
            float sel_d = ((ln & 3) == 0) ? vd0 : ((ln & 3) == 1) ? vd1 : ((ln & 3) == 2) ? vd2 : vd3;
            if (ok && ln < 4)              s_src[row * N_HEADS + ln]       = sel_s;
            if (ok && ln >= 4 && ln < 8)   s_dst[row * N_HEADS + (ln & 3)] = sel_d;

            #pragma unroll
            for (int cf = 0; cf < 8; ++cf) {
                float v = acc[cf][r];
                float o = __shfl_xor(v, 1);
                if (!(ln & 1) && ok) {
                    zb[(size_t)row * 64 + cf * 8 + (ln >> 1)] = pack_bf2(v, o);
                }
            }
        }
    }
}

// ---------------------------------------------------------------------------
// Pass A: bucket-scatter with LDS aggregation (dense scratch writes).
// ---------------------------------------------------------------------------
__global__ __launch_bounds__(256) void bucketA_kernel(
    const int* __restrict__ src, const int* __restrict__ dst,
    int* __restrict__ bucket_fill, unsigned int* __restrict__ scratch,
    int n_edges, int nbuck)
{
    __shared__ int bhist[512];
    __shared__ int boff[512];
    __shared__ int goff[512];
    __shared__ int bcur[512];
    __shared__ int stmp[256];
    __shared__ unsigned int lpair[CHUNK];   // 32 KB

    const int t  = threadIdx.x;
    const int e0 = blockIdx.x * CHUNK;
    const int n  = min(CHUNK, n_edges - e0);

    bhist[t] = 0; bhist[t + 256] = 0;
    __syncthreads();

    for (int i = t; i < n; i += 256) {
        atomicAdd(&bhist[dst[e0 + i] >> BSHIFT], 1);
    }
    __syncthreads();

    int a0 = bhist[2 * t], a1 = bhist[2 * t + 1];
    int s  = a0 + a1;
    int x  = s;
    stmp[t] = x;
    __syncthreads();
    for (int off = 1; off < 256; off <<= 1) {
        int y = (t >= off) ? stmp[t - off] : 0;
        __syncthreads();
        x += y;
        stmp[t] = x;
        __syncthreads();
    }
    int excl = x - s;
    boff[2 * t]     = excl;
    boff[2 * t + 1] = excl + a0;
    bcur[2 * t]     = excl;
    bcur[2 * t + 1] = excl + a0;

    #pragma unroll
    for (int b = t; b < 512; b += 256) {
        int c = bhist[b];
        goff[b] = (c > 0) ? (b * CAP + atomicAdd(&bucket_fill[b], c)) : 0;
    }
    __syncthreads();

    for (int i = t; i < n; i += 256) {
        int d  = dst[e0 + i];
        int sv = src[e0 + i];
        int p  = atomicAdd(&bcur[d >> BSHIFT], 1);
        lpair[p] = ((unsigned int)d << 16) | (unsigned int)sv;
    }
    __syncthreads();

    const int lim = nbuck * CAP - 1;
    for (int i = t; i < n; i += 256) {
        unsigned int u = lpair[i];
        int b = (int)(u >> 16) >> BSHIFT;
        int addr = goff[b] + (i - boff[b]);
        scratch[min(addr, lim)] = u;
    }
}

// ---------------------------------------------------------------------------
// Pass B: one block per bucket, PURE LDS work + dense writes (round-10 form,
// NO global histogram atomics). Redundant bucket scan -> row0; per-node LDS
// histogram + scan -> row_start; placement writes packed (dst<<16|src).
// ---------------------------------------------------------------------------
__global__ __launch_bounds__(256) void bucketB_kernel(
    const unsigned int* __restrict__ scratch,
    const int* __restrict__ bucket_fill,
    int* __restrict__ row_start,
    unsigned int* __restrict__ sorted_pair,
    int n_nodes, int nbuck, int n_edges)
{
    __shared__ int pref[512];
    __shared__ int lhist[128];
    __shared__ int lcur[128];
    __shared__ int stmp[256];
    __shared__ unsigned int ent[CAP];   // 16 KB

    const int b = blockIdx.x;
    const int t = threadIdx.x;

    // --- redundant exclusive scan of bucket_fill -> pref[] ---
    {
        int a0 = (2 * t     < nbuck) ? min(bucket_fill[2 * t],     CAP) : 0;
        int a1 = (2 * t + 1 < nbuck) ? min(bucket_fill[2 * t + 1], CAP) : 0;
        int s = a0 + a1;
        int x = s;
        stmp[t] = x;
        __syncthreads();
        for (int off = 1; off < 256; off <<= 1) {
            int y = (t >= off) ? stmp[t - off] : 0;
            __syncthreads();
            x += y;
            stmp[t] = x;
            __syncthreads();
        }
        int excl = x - s;
        pref[2 * t]     = excl;
        pref[2 * t + 1] = excl + a0;
    }
    __syncthreads();

    const int cnt_b = min(bucket_fill[b], CAP);
    const int row0  = pref[b];
    const unsigned int* sb = scratch + (size_t)b * CAP;

    if (b == 0 && t == 0) row_start[n_nodes] = n_edges;

    if (t < 128) lhist[t] = 0;
    __syncthreads();

    for (int i = t; i < cnt_b; i += 256) {
        unsigned int u = sb[i];
        ent[i] = u;
        atomicAdd(&lhist[(u >> 16) & (BUCK_NODES - 1)], 1);
    }
    __syncthreads();

    int v = (t < 128) ? lhist[t] : 0;
    int x = v;
    stmp[t] = x;
    __syncthreads();
    for (int off = 1; off < 128; off <<= 1) {
        int y = (t >= off) ? stmp[t - off] : 0;
        __syncthreads();
        x += y;
        stmp[t] = x;
        __syncthreads();
    }
    if (t < 128) {
        int excl = x - v;
        lcur[t] = excl;
        int node = b * BUCK_NODES + t;
        if (node < n_nodes) row_start[node] = row0 + excl;
    }
    __syncthreads();

    for (int i = t; i < cnt_b; i += 256) {
        unsigned int u = ent[i];
        int dl = (u >> 16) & (BUCK_NODES - 1);
        int r = atomicAdd(&lcur[dl], 1);
        sorted_pair[row0 + r] = u;
    }
}

// ---------------------------------------------------------------------------
// flat per-edge kernel (full TLP): reads sorted_pair densely, gathers
// per-node scores, computes bf16 softmax numerators for all 4 heads,
// writes packed_ex densely and rewrites sorted_pair -> plain src in place.
// ---------------------------------------------------------------------------
__global__ __launch_bounds__(256) void ex_kernel(
    unsigned int* __restrict__ sorted_pair,
    const float* __restrict__ s_src, const float* __restrict__ s_dst,
    uint2* __restrict__ packed_ex, int n_edges)
{
    int i = blockIdx.x * 256 + threadIdx.x;
    if (i >= n_edges) return;
    unsigned int u = sorted_pair[i];
    int sv = (int)(u & 0xFFFFu);
    int dn = (int)(u >> 16);
    float4 ss = *(const float4*)&s_src[sv * N_HEADS];
    float4 sd = *(const float4*)&s_dst[dn * N_HEADS];
    float e0 = ss.x + sd.x; e0 = fmaxf(e0, NEG_SLOPE * e0);
    float e1 = ss.y + sd.y; e1 = fmaxf(e1, NEG_SLOPE * e1);
    float e2 = ss.z + sd.z; e2 = fmaxf(e2, NEG_SLOPE * e2);
    float e3 = ss.w + sd.w; e3 = fmaxf(e3, NEG_SLOPE * e3);
    uint2 pw;
    pw.x = pack_bf2(__expf(e0), __expf(e1));
    pw.y = pack_bf2(__expf(e2), __expf(e3));
    packed_ex[i] = pw;
    sorted_pair[i] = (unsigned int)sv;
}

// ---------------------------------------------------------------------------
// fused aggregate: TWO consecutive nodes per wave (no perm). Per node:
// 2 edge slots x 4-deep unroll = 8 edges in flight. Softmax numerators
// precomputed (bf16 pairs) -> no exp / no random score gather here.
// ---------------------------------------------------------------------------
__global__ __launch_bounds__(256) void gather_kernel(
    const int* __restrict__ sorted_src, const int* __restrict__ row_start,
    const unsigned int* __restrict__ packed_ex,
    const unsigned int* __restrict__ zb,
    float* __restrict__ out, int n_nodes)
{
    int wave = (blockIdx.x * 256 + threadIdx.x) >> 6;
    int lane = threadIdx.x & 63;
    int half = lane >> 5;
    int node = wave * 2 + half;
    int g2   = (lane >> 4) & 1;      // edge slot 0..1
    int q    = lane & 15;            // col group: cols 8q..8q+7
    int hh   = q >> 2;               // head
    int exsel = hh >> 1;             // which word of the uint2
    bool exhi = (hh & 1);            // which bf16 half

    const bool valid = (node < n_nodes);
    const int nclamp = min(node, n_nodes - 1);
    const int b0 = row_start[nclamp];
    int deg = row_start[nclamp + 1] - b0;
    if (!valid) deg = 0;

    f32x2 acc2[4];
    #pragma unroll
    for (int i = 0; i < 4; ++i) acc2[i] = (f32x2){0.f, 0.f};
    float den = 0.0f;

    if (deg > 0) {
        const int* sp = sorted_src + b0;
        const unsigned int* pex = packed_ex + (size_t)b0 * 2 + exsel;
        const int dm1 = deg - 1;

        for (int p = 0; p < deg; p += 8) {
            int i0 = p + g2, i1 = p + 2 + g2, i2 = p + 4 + g2, i3 = p + 6 + g2;
            int c0 = min(i0, dm1), c1 = min(i1, dm1);
            int c2 = min(i2, dm1), c3 = min(i3, dm1);
            int s0 = sp[c0];
            int s1 = sp[c1];
            int s2 = sp[c2];
            int s3 = sp[c3];
            unsigned int w0 = pex[c0 * 2];
            unsigned int w1 = pex[c1 * 2];
            unsigned int w2 = pex[c2 * 2];
            unsigned int w3 = pex[c3 * 2];
            uint4 u0 = *(const uint4*)&zb[(size_t)s0 * 64 + q * 4];
            uint4 u1 = *(const uint4*)&zb[(size_t)s1 * 64 + q * 4];
            uint4 u2 = *(const uint4*)&zb[(size_t)s2 * 64 + q * 4];
            uint4 u3 = *(const uint4*)&zb[(size_t)s3 * 64 + q * 4];

            float x0 = exhi ? bf_hi(w0) : bf_lo(w0);
            float x1 = exhi ? bf_hi(w1) : bf_lo(w1);
            float x2 = exhi ? bf_hi(w2) : bf_lo(w2);
            float x3 = exhi ? bf_hi(w3) : bf_lo(w3);
            if (i0 > dm1) x0 = 0.0f;
            if (i1 > dm1) x1 = 0.0f;
            if (i2 > dm1) x2 = 0.0f;
            if (i3 > dm1) x3 = 0.0f;
            den += (x0 + x1) + (x2 + x3);

            f32x2 xv;
            xv = (f32x2){x0, x0};
            acc2[0] += xv * bfpair(u0.x);
            acc2[1] += xv * bfpair(u0.y);
            acc2[2] += xv * bfpair(u0.z);
            acc2[3] += xv * bfpair(u0.w);
            xv = (f32x2){x1, x1};
            acc2[0] += xv * bfpair(u1.x);
            acc2[1] += xv * bfpair(u1.y);
            acc2[2] += xv * bfpair(u1.z);
            acc2[3] += xv * bfpair(u1.w);
            xv = (f32x2){x2, x2};
            acc2[0] += xv * bfpair(u2.x);
            acc2[1] += xv * bfpair(u2.y);
            acc2[2] += xv * bfpair(u2.z);
            acc2[3] += xv * bfpair(u2.w);
            xv = (f32x2){x3, x3};
            acc2[0] += xv * bfpair(u3.x);
            acc2[1] += xv * bfpair(u3.y);
            acc2[2] += xv * bfpair(u3.z);
            acc2[3] += xv * bfpair(u3.w);
        }
    }

    // reduce across the 2 edge slots (lane bit 4; stays within 32-lane half)
    #pragma unroll
    for (int i = 0; i < 4; ++i) {
        acc2[i].x += __shfl_xor(acc2[i].x, 16);
        acc2[i].y += __shfl_xor(acc2[i].y, 16);
    }
    den += __shfl_xor(den, 16);

    if (g2 == 0 && valid) {
        float inv = (deg > 0) ? 1.0f / den : 0.0f;
        float4 v0 = make_float4(acc2[0].x * inv, acc2[0].y * inv, acc2[1].x * inv, acc2[1].y * inv);
        float4 v1 = make_float4(acc2[2].x * inv, acc2[2].y * inv, acc2[3].x * inv, acc2[3].y * inv);
        float4* op = (float4*)&out[(size_t)node * OUT_DIM + q * 8];
        op[0] = v0;
        op[1] = v1;
    }
}

// ---------------------------------------------------------------------------
extern "C" void kernel_launch(void* const* d_in, const int* in_sizes, int n_in,
                              void* d_out, int out_size, void* d_ws, size_t ws_size,
                              hipStream_t stream)
{
    const float* h      = (const float*)d_in[0];
    const float* fc_w   = (const float*)d_in[1];
    const float* attn_w = (const float*)d_in[2];
    const int*   src    = (const int*)d_in[3];
    const int*   dst    = (const int*)d_in[4];

    const int n_nodes = in_sizes[0] / IN_DIM;   // 50000
    const int n_edges = in_sizes[3];            // 800000
    const int nbuck   = (n_nodes + BUCK_NODES - 1) / BUCK_NODES;   // 391

    float* out = (float*)d_out;

    // workspace layout (int units; packed_ex kept 8B-aligned)
    char* ws = (char*)d_ws;
    unsigned int* zb      = (unsigned int*)ws;                          // n_nodes*64 u32
    float* s_src          = (float*)(zb + (size_t)n_nodes * 64);        // n_nodes*4
    float* s_dst          = s_src + (size_t)n_nodes * N_HEADS;          // n_nodes*4
    int*   row_start      = (int*)(s_dst + (size_t)n_nodes * N_HEADS);  // n_nodes+1 (+pad)
    int*   bucket_fill    = row_start + n_nodes + 16;                   // nbuck (+pad, even)
    unsigned int* sorted_pair = (unsigned int*)(bucket_fill + nbuck + 17); // n_edges (becomes sorted_src)
    uint2* packed_ex      = (uint2*)(sorted_pair + n_edges + 16);       // n_edges uint2 (8B-aligned)
    unsigned int* scratch = (unsigned int*)(packed_ex + n_edges);       // nbuck*CAP
    unsigned short* wl_g  = (unsigned short*)(scratch + (size_t)nbuck * CAP); // 32768 bf16

    // 1. setup: W prep + zero bucket_fill
    setup_kernel<<<128, 256, 0, stream>>>(fc_w, wl_g, bucket_fill, nbuck);

    // 2. bucket pass A (dst-bucket scatter, dense writes)
    bucketA_kernel<<<(n_edges + CHUNK - 1) / CHUNK, 256, 0, stream>>>(
        src, dst, bucket_fill, scratch, n_edges, nbuck);

    // 3. bucket pass B: CSR finalize (pure LDS + dense writes, no atomics)
    bucketB_kernel<<<nbuck, 256, 0, stream>>>(
        scratch, bucket_fill, row_start, sorted_pair, n_nodes, nbuck, n_edges);

    // 4. dense phase: MFMA GEMM (fused scores + bf16 z), 256 rows/block
    gemm_mfma_kernel<<<(n_nodes + 255) / 256, 512, 0, stream>>>(
        h, wl_g, attn_w, zb, s_src, s_dst, n_nodes);

    // 5. flat per-edge softmax numerators (full TLP)
    ex_kernel<<<(n_edges + 255) / 256, 256, 0, stream>>>(
        sorted_pair, s_src, s_dst, packed_ex, n_edges);

    // 6. fused aggregate, 2 consecutive nodes per wave
    {
        int waves = (n_nodes + 1) / 2;
        int blocks = (waves * 64 + 255) / 256;
        gather_kernel<<<blocks, 256, 0, stream>>>(
            (const int*)sorted_pair, row_start,
            (const unsigned int*)packed_ex, zb, out, n_nodes);
    }
}

// Round 14
// 92.109 us; speedup vs baseline: 4.2095x; 1.0556x over previous
//
#include <hip/hip_runtime.h>
#include <hip/hip_bf16.h>
#include <math.h>

#define N_HEADS 4
#define D_HEAD 32
#define IN_DIM 256
#define OUT_DIM (N_HEADS * D_HEAD)   // 128
#define NEG_SLOPE 0.01f

// CSR-build geometry: 128 nodes per bucket, padded scratch regions.
// NOTE: packing (dst<<16 | src) requires n_nodes < 65536 (here 50000).
#define BSHIFT 7
#define BUCK_NODES 128
#define CAP 4096            // scratch slots per bucket (avg fill ~2048)
#define CHUNK 8192          // edges per pass-A block

typedef __attribute__((ext_vector_type(8))) short bf16x8;
typedef __attribute__((ext_vector_type(4))) float f32x4;
typedef __attribute__((ext_vector_type(2))) float f32x2;

// round-to-nearest-even f32 -> bf16 (as u16) — cold path only (setup)
static __device__ __forceinline__ unsigned short f2bf(float x)
{
    unsigned int u = __float_as_uint(x);
    u = u + 0x7FFFu + ((u >> 16) & 1u);
    return (unsigned short)(u >> 16);
}

// hot-path pack: 2 floats -> packed bf16x2 (v_cvt_pk_bf16_f32)
static __device__ __forceinline__ unsigned int pack_bf2(float a, float b)
{
    union { __hip_bfloat162 b2; unsigned int u; } r;
    r.b2 = __float22bfloat162_rn(make_float2(a, b));
    return r.u;
}

static __device__ __forceinline__ f32x2 bfpair(unsigned int u)
{
    f32x2 r;
    r.x = __uint_as_float(u << 16);
    r.y = __uint_as_float(u & 0xFFFF0000u);
    return r;
}

// ---------------------------------------------------------------------------
// setup: arrange fc_w into MFMA-B-fragment order (bf16); zero bucket_fill.
// wl[((cf*8+kf)*64 + l)*8 + j] = B[kf*32 + 8*(l>>4) + j][cf*16 + (l&15)]
// ---------------------------------------------------------------------------
__global__ void setup_kernel(const float* __restrict__ fc_w,
                             unsigned short* __restrict__ wl,
                             int* __restrict__ bucket_fill, int nbuck)
{
    int o = blockIdx.x * blockDim.x + threadIdx.x;   // 0..32767
    if (o < nbuck) bucket_fill[o] = 0;
    if (o >= 32768) return;
    int j  = o & 7;
    int l  = (o >> 3) & 63;
    int kf = (o >> 9) & 7;
    int cf = (o >> 12) & 7;
    int k   = kf * 32 + (l >> 4) * 8 + j;
    int col = cf * 16 + (l & 15);
    int hh = col >> 5, d = col & 31;
    wl[o] = f2bf(fc_w[hh * 8192 + k * 32 + d]);
}

// ---------------------------------------------------------------------------
// MFMA GEMM: 128 rows/block (16/wave, 8 waves, grid=391 > 256 CUs).
// A-fragments direct from global (v_cvt_pk_bf16_f32); B from LDS-staged wl.
// Epilogue: per-head scores (shfl) + bf16 z pack.
// ---------------------------------------------------------------------------
__global__ __launch_bounds__(512, 4) void gemm_mfma_kernel(
    const float* __restrict__ h, const unsigned short* __restrict__ wl,
    const float* __restrict__ attn_w,
    unsigned int* __restrict__ zb,
    float* __restrict__ s_src, float* __restrict__ s_dst,
    int n_nodes)
{
    __shared__ unsigned short wls[32768];   // 64 KB

    const int t = threadIdx.x;

    #pragma unroll
    for (int it = 0; it < 8; ++it) {
        ((uint4*)wls)[t + it * 512] = ((const uint4*)wl)[t + it * 512];
    }
    __syncthreads();

    const int w  = t >> 6;          // wave 0..7
    const int l  = t & 63;
    const int g  = l >> 4;
    const int ln = l & 15;
    const int m0 = blockIdx.x * 128 + w * 16;

    const int arow = min(m0 + ln, n_nodes - 1);
    const float4* hrow = (const float4*)(h + (size_t)arow * IN_DIM);

    f32x4 acc[8];
    #pragma unroll
    for (int cf = 0; cf < 8; ++cf) acc[cf] = (f32x4){0.f, 0.f, 0.f, 0.f};

    #pragma unroll
    for (int kf = 0; kf < 8; ++kf) {
        float4 alo = hrow[kf * 8 + g * 2];
        float4 ahi = hrow[kf * 8 + g * 2 + 1];
        union { unsigned int u[4]; bf16x8 v; } fa;
        fa.u[0] = pack_bf2(alo.x, alo.y);
        fa.u[1] = pack_bf2(alo.z, alo.w);
        fa.u[2] = pack_bf2(ahi.x, ahi.y);
        fa.u[3] = pack_bf2(ahi.z, ahi.w);

        #pragma unroll
        for (int cf = 0; cf < 8; ++cf) {
            bf16x8 fb = *(const bf16x8*)&wls[((cf * 8 + kf) * 64 + l) * 8];
            acc[cf] = __builtin_amdgcn_mfma_f32_16x16x32_bf16(fa.v, fb, acc[cf], 0, 0, 0);
        }
    }

    float aw_s[8], aw_d[8];
    #pragma unroll
    for (int cf = 0; cf < 8; ++cf) {
        int col = cf * 16 + ln;
        int hh = col >> 5, d = col & 31;
        aw_s[cf] = attn_w[hh * 64 + d];
        aw_d[cf] = attn_w[hh * 64 + 32 + d];
    }

    #pragma unroll
    for (int r = 0; r < 4; ++r) {
        const int row = m0 + 4 * g + r;
        const bool ok = (row < n_nodes);

        float vs0 = acc[0][r] * aw_s[0] + acc[1][r] * aw_s[1];
        float vs1 = acc[2][r] * aw_s[2] + acc[3][r] * aw_s[3];
        float vs2 = acc[4][r] * aw_s[4] + acc[5][r] * aw_s[5];
        float vs3 = acc[6][r] * aw_s[6] + acc[7][r] * aw_s[7];
        float vd0 = acc[0][r] * aw_d[0] + acc[1][r] * aw_d[1];
        float vd1 = acc[2][r] * aw_d[2] + acc[3][r] * aw_d[3];
        float vd2 = acc[4][r] * aw_d[4] + acc[5][r] * aw_d[5];
        float vd3 = acc[6][r] * aw_d[6] + acc[7][r] * aw_d[7];
        #pragma unroll
        for (int mk = 1; mk < 16; mk <<= 1) {
            vs0 += __shfl_xor(vs0, mk); vs1 += __shfl_xor(vs1, mk);
            vs2 += __shfl_xor(vs2, mk); vs3 += __shfl_xor(vs3, mk);
            vd0 += __shfl_xor(vd0, mk); vd1 += __shfl_xor(vd1, mk);
            vd2 += __shfl_xor(vd2, mk); vd3 += __shfl_xor(vd3, mk);
        }
        float sel_s = (ln == 0) ? vs0 : (ln == 1) ? vs1 : (ln == 2) ? vs2 : vs3;
        float sel_d = ((ln & 3) == 0) ? vd0 : ((ln & 3) == 1) ? vd1 : ((ln & 3) == 2) ? vd2 : vd3;
        if (ok && ln < 4)              s_src[row * N_HEADS + ln]       = sel_s;
        if (ok && ln >= 4 && ln < 8)   s_dst[row * N_HEADS + (ln & 3)] = sel_d;

        #pragma unroll
        for (int cf = 0; cf < 8; ++cf) {
            float v = acc[cf][r];
            float o = __shfl_xor(v, 1);
            if (!(ln & 1) && ok) {
                zb[(size_t)row * 64 + cf * 8 + (ln >> 1)] = pack_bf2(v, o);
            }
        }
    }
}

// ---------------------------------------------------------------------------
// Pass A: bucket-scatter with LDS aggregation (dense scratch writes).
// ---------------------------------------------------------------------------
__global__ __launch_bounds__(256) void bucketA_kernel(
    const int* __restrict__ src, const int* __restrict__ dst,
    int* __restrict__ bucket_fill, unsigned int* __restrict__ scratch,
    int n_edges, int nbuck)
{
    __shared__ int bhist[512];
    __shared__ int boff[512];
    __shared__ int goff[512];
    __shared__ int bcur[512];
    __shared__ int stmp[256];
    __shared__ unsigned int lpair[CHUNK];   // 32 KB

    const int t  = threadIdx.x;
    const int e0 = blockIdx.x * CHUNK;
    const int n  = min(CHUNK, n_edges - e0);

    bhist[t] = 0; bhist[t + 256] = 0;
    __syncthreads();

    for (int i = t; i < n; i += 256) {
        atomicAdd(&bhist[dst[e0 + i] >> BSHIFT], 1);
    }
    __syncthreads();

    int a0 = bhist[2 * t], a1 = bhist[2 * t + 1];
    int s  = a0 + a1;
    int x  = s;
    stmp[t] = x;
    __syncthreads();
    for (int off = 1; off < 256; off <<= 1) {
        int y = (t >= off) ? stmp[t - off] : 0;
        __syncthreads();
        x += y;
        stmp[t] = x;
        __syncthreads();
    }
    int excl = x - s;
    boff[2 * t]     = excl;
    boff[2 * t + 1] = excl + a0;
    bcur[2 * t]     = excl;
    bcur[2 * t + 1] = excl + a0;

    #pragma unroll
    for (int b = t; b < 512; b += 256) {
        int c = bhist[b];
        goff[b] = (c > 0) ? (b * CAP + atomicAdd(&bucket_fill[b], c)) : 0;
    }
    __syncthreads();

    for (int i = t; i < n; i += 256) {
        int d  = dst[e0 + i];
        int sv = src[e0 + i];
        int p  = atomicAdd(&bcur[d >> BSHIFT], 1);
        lpair[p] = ((unsigned int)d << 16) | (unsigned int)sv;
    }
    __syncthreads();

    const int lim = nbuck * CAP - 1;
    for (int i = t; i < n; i += 256) {
        unsigned int u = lpair[i];
        int b = (int)(u >> 16) >> BSHIFT;
        int addr = goff[b] + (i - boff[b]);
        scratch[min(addr, lim)] = u;
    }
}

// ---------------------------------------------------------------------------
// Pass B: one block per bucket, pure LDS work + dense writes. Redundant
// bucket scan -> row0; per-node LDS histogram + scan -> row_start; placement
// writes plain src into sorted_src.
// ---------------------------------------------------------------------------
__global__ __launch_bounds__(256) void bucketB_kernel(
    const unsigned int* __restrict__ scratch,
    const int* __restrict__ bucket_fill,
    int* __restrict__ row_start,
    int* __restrict__ sorted_src,
    int n_nodes, int nbuck, int n_edges)
{
    __shared__ int pref[512];
    __shared__ int lhist[128];
    __shared__ int lcur[128];
    __shared__ int stmp[256];
    __shared__ unsigned int ent[CAP];   // 16 KB

    const int b = blockIdx.x;
    const int t = threadIdx.x;

    // --- redundant exclusive scan of bucket_fill -> pref[] ---
    {
        int a0 = (2 * t     < nbuck) ? min(bucket_fill[2 * t],     CAP) : 0;
        int a1 = (2 * t + 1 < nbuck) ? min(bucket_fill[2 * t + 1], CAP) : 0;
        int s = a0 + a1;
        int x = s;
        stmp[t] = x;
        __syncthreads();
        for (int off = 1; off < 256; off <<= 1) {
            int y = (t >= off) ? stmp[t - off] : 0;
            __syncthreads();
            x += y;
            stmp[t] = x;
            __syncthreads();
        }
        int excl = x - s;
        pref[2 * t]     = excl;
        pref[2 * t + 1] = excl + a0;
    }
    __syncthreads();

    const int cnt_b = min(bucket_fill[b], CAP);
    const int row0  = pref[b];
    const unsigned int* sb = scratch + (size_t)b * CAP;

    if (b == 0 && t == 0) row_start[n_nodes] = n_edges;

    if (t < 128) lhist[t] = 0;
    __syncthreads();

    for (int i = t; i < cnt_b; i += 256) {
        unsigned int u = sb[i];
        ent[i] = u;
        atomicAdd(&lhist[(u >> 16) & (BUCK_NODES - 1)], 1);
    }
    __syncthreads();

    int v = (t < 128) ? lhist[t] : 0;
    int x = v;
    stmp[t] = x;
    __syncthreads();
    for (int off = 1; off < 128; off <<= 1) {
        int y = (t >= off) ? stmp[t - off] : 0;
        __syncthreads();
        x += y;
        stmp[t] = x;
        __syncthreads();
    }
    if (t < 128) {
        int excl = x - v;
        lcur[t] = excl;
        int node = b * BUCK_NODES + t;
        if (node < n_nodes) row_start[node] = row0 + excl;
    }
    __syncthreads();

    for (int i = t; i < cnt_b; i += 256) {
        unsigned int u = ent[i];
        int dl = (u >> 16) & (BUCK_NODES - 1);
        int r = atomicAdd(&lcur[dl], 1);
        sorted_src[row0 + r] = (int)(u & 0xFFFFu);
    }
}

// ---------------------------------------------------------------------------
// fused single-pass softmax + aggregate. TWO nodes per wave:
// lanes 0-31 -> node 2*wid, lanes 32-63 -> node 2*wid+1.
// Per node: 2 edge slots (lane bit 4) x 4-deep unroll = 8 edges in flight.
// Lane owns 8 cols (uint4 of bf16x2).
// ---------------------------------------------------------------------------
__global__ __launch_bounds__(256) void gather_kernel(
    const int* __restrict__ sorted_src, const int* __restrict__ row_start,
    const unsigned int* __restrict__ zb,
    const float* __restrict__ s_src, const float* __restrict__ s_dst,
    float* __restrict__ out, int n_nodes)
{
    int wave = (blockIdx.x * 256 + threadIdx.x) >> 6;
    int lane = threadIdx.x & 63;
    int half = lane >> 5;
    int node = wave * 2 + half;
    int g2   = (lane >> 4) & 1;      // edge slot 0..1
    int q    = lane & 15;            // col group: cols 8q..8q+7
    int hh   = q >> 2;               // head

    const bool valid = (node < n_nodes);
    const int nclamp = min(node, n_nodes - 1);
    const int b0 = row_start[nclamp];
    int deg = row_start[nclamp + 1] - b0;
    if (!valid) deg = 0;

    f32x2 acc2[4];
    #pragma unroll
    for (int i = 0; i < 4; ++i) acc2[i] = (f32x2){0.f, 0.f};
    float den = 0.0f;

    if (deg > 0) {
        const int* sp = sorted_src + b0;
        const float sdst = s_dst[nclamp * N_HEADS + hh];
        const int dm1 = deg - 1;

        for (int p = 0; p < deg; p += 8) {
            int i0 = p + g2, i1 = p + 2 + g2, i2 = p + 4 + g2, i3 = p + 6 + g2;
            int s0 = sp[min(i0, dm1)];
            int s1 = sp[min(i1, dm1)];
            int s2 = sp[min(i2, dm1)];
            int s3 = sp[min(i3, dm1)];

            float f0 = s_src[s0 * N_HEADS + hh];
            float f1 = s_src[s1 * N_HEADS + hh];
            float f2 = s_src[s2 * N_HEADS + hh];
            float f3 = s_src[s3 * N_HEADS + hh];
            uint4 u0 = *(const uint4*)&zb[(size_t)s0 * 64 + q * 4];
            uint4 u1 = *(const uint4*)&zb[(size_t)s1 * 64 + q * 4];
            uint4 u2 = *(const uint4*)&zb[(size_t)s2 * 64 + q * 4];
            uint4 u3 = *(const uint4*)&zb[(size_t)s3 * 64 + q * 4];

            float e0 = f0 + sdst; e0 = fmaxf(e0, NEG_SLOPE * e0);
            float e1 = f1 + sdst; e1 = fmaxf(e1, NEG_SLOPE * e1);
            float e2 = f2 + sdst; e2 = fmaxf(e2, NEG_SLOPE * e2);
            float e3 = f3 + sdst; e3 = fmaxf(e3, NEG_SLOPE * e3);
            float x0 = (i0 <= dm1) ? __expf(e0) : 0.0f;
            float x1 = (i1 <= dm1) ? __expf(e1) : 0.0f;
            float x2 = (i2 <= dm1) ? __expf(e2) : 0.0f;
            float x3 = (i3 <= dm1) ? __expf(e3) : 0.0f;
            den += (x0 + x1) + (x2 + x3);

            f32x2 xv;
            xv = (f32x2){x0, x0};
            acc2[0] += xv * bfpair(u0.x);
            acc2[1] += xv * bfpair(u0.y);
            acc2[2] += xv * bfpair(u0.z);
            acc2[3] += xv * bfpair(u0.w);
            xv = (f32x2){x1, x1};
            acc2[0] += xv * bfpair(u1.x);
            acc2[1] += xv * bfpair(u1.y);
            acc2[2] += xv * bfpair(u1.z);
            acc2[3] += xv * bfpair(u1.w);
            xv = (f32x2){x2, x2};
            acc2[0] += xv * bfpair(u2.x);
            acc2[1] += xv * bfpair(u2.y);
            acc2[2] += xv * bfpair(u2.z);
            acc2[3] += xv * bfpair(u2.w);
            xv = (f32x2){x3, x3};
            acc2[0] += xv * bfpair(u3.x);
            acc2[1] += xv * bfpair(u3.y);
            acc2[2] += xv * bfpair(u3.z);
            acc2[3] += xv * bfpair(u3.w);
        }
    }

    // reduce across the 2 edge slots (lane bit 4; stays within 32-lane half)
    #pragma unroll
    for (int i = 0; i < 4; ++i) {
        acc2[i].x += __shfl_xor(acc2[i].x, 16);
        acc2[i].y += __shfl_xor(acc2[i].y, 16);
    }
    den += __shfl_xor(den, 16);

    if (g2 == 0 && valid) {
        float inv = (deg > 0) ? 1.0f / den : 0.0f;
        float4 v0 = make_float4(acc2[0].x * inv, acc2[0].y * inv, acc2[1].x * inv, acc2[1].y * inv);
        float4 v1 = make_float4(acc2[2].x * inv, acc2[2].y * inv, acc2[3].x * inv, acc2[3].y * inv);
        float4* op = (float4*)&out[(size_t)node * OUT_DIM + q * 8];
        op[0] = v0;
        op[1] = v1;
    }
}

// ---------------------------------------------------------------------------
extern "C" void kernel_launch(void* const* d_in, const int* in_sizes, int n_in,
                              void* d_out, int out_size, void* d_ws, size_t ws_size,
                              hipStream_t stream)
{
    const float* h      = (const float*)d_in[0];
    const float* fc_w   = (const float*)d_in[1];
    const float* attn_w = (const float*)d_in[2];
    const int*   src    = (const int*)d_in[3];
    const int*   dst    = (const int*)d_in[4];

    const int n_nodes = in_sizes[0] / IN_DIM;   // 50000
    const int n_edges = in_sizes[3];            // 800000
    const int nbuck   = (n_nodes + BUCK_NODES - 1) / BUCK_NODES;   // 391

    float* out = (float*)d_out;

    // workspace layout (all 4-byte types, 16B-aligned blocks)
    char* ws = (char*)d_ws;
    unsigned int* zb      = (unsigned int*)ws;                          // n_nodes*64 u32
    float* s_src          = (float*)(zb + (size_t)n_nodes * 64);        // n_nodes*4
    float* s_dst          = s_src + (size_t)n_nodes * N_HEADS;          // n_nodes*4
    int*   row_start      = (int*)(s_dst + (size_t)n_nodes * N_HEADS);  // n_nodes+1 (+pad)
    int*   bucket_fill    = row_start + n_nodes + 16;                   // nbuck
    int*   sorted_src     = bucket_fill + nbuck + 17;                   // n_edges
    unsigned int* scratch = (unsigned int*)(sorted_src + n_edges + 16); // nbuck*CAP
    unsigned short* wl_g  = (unsigned short*)(scratch + (size_t)nbuck * CAP); // 32768 bf16

    // 1. setup: W prep + zero bucket_fill
    setup_kernel<<<128, 256, 0, stream>>>(fc_w, wl_g, bucket_fill, nbuck);

    // 2. bucket pass A (dst-bucket scatter, dense writes)
    bucketA_kernel<<<(n_edges + CHUNK - 1) / CHUNK, 256, 0, stream>>>(
        src, dst, bucket_fill, scratch, n_edges, nbuck);

    // 3. bucket pass B: CSR finalize (pure LDS + dense writes, no atomics)
    bucketB_kernel<<<nbuck, 256, 0, stream>>>(
        scratch, bucket_fill, row_start, sorted_src, n_nodes, nbuck, n_edges);

    // 4. dense phase: MFMA GEMM (fused scores + bf16 z), 128 rows/block
    gemm_mfma_kernel<<<(n_nodes + 127) / 128, 512, 0, stream>>>(
        h, wl_g, attn_w, zb, s_src, s_dst, n_nodes);

    // 5. fused single-pass softmax + aggregate, 2 consecutive nodes per wave
    {
        int waves = (n_nodes + 1) / 2;
        int blocks = (waves * 64 + 255) / 256;
        gather_kernel<<<blocks, 256, 0, stream>>>(
            sorted_src, row_start, zb, s_src, s_dst, out, n_nodes);
    }
}

// Round 15
// 70.795 us; speedup vs baseline: 5.4769x; 1.3011x over previous
//
#include <hip/hip_runtime.h>
#include <hip/hip_bf16.h>
#include <math.h>

#define N_HEADS 4
#define D_HEAD 32
#define IN_DIM 256
#define OUT_DIM (N_HEADS * D_HEAD)   // 128
#define NEG_SLOPE 0.01f

// CSR-build geometry: 128 nodes per bucket, padded scratch regions.
// NOTE: packing (dst<<16 | src) requires n_nodes < 65536 (here 50000).
#define BSHIFT 7
#define BUCK_NODES 128
#define CAP 4096            // scratch slots per bucket (avg fill ~2048)
#define CHUNK 8192          // edges per bucketA block

typedef __attribute__((ext_vector_type(8))) short bf16x8;
typedef __attribute__((ext_vector_type(4))) float f32x4;
typedef __attribute__((ext_vector_type(2))) float f32x2;

// round-to-nearest-even f32 -> bf16 (as u16) — cold path only (setup)
static __device__ __forceinline__ unsigned short f2bf(float x)
{
    unsigned int u = __float_as_uint(x);
    u = u + 0x7FFFu + ((u >> 16) & 1u);
    return (unsigned short)(u >> 16);
}

// hot-path pack: 2 floats -> packed bf16x2 (v_cvt_pk_bf16_f32)
static __device__ __forceinline__ unsigned int pack_bf2(float a, float b)
{
    union { __hip_bfloat162 b2; unsigned int u; } r;
    r.b2 = __float22bfloat162_rn(make_float2(a, b));
    return r.u;
}

static __device__ __forceinline__ f32x2 bfpair(unsigned int u)
{
    f32x2 r;
    r.x = __uint_as_float(u << 16);
    r.y = __uint_as_float(u & 0xFFFF0000u);
    return r;
}

// ---------------------------------------------------------------------------
// setup: arrange fc_w into MFMA-B-fragment order (bf16); zero bucket_fill.
// wl[((cf*8+kf)*64 + l)*8 + j] = B[kf*32 + 8*(l>>4) + j][cf*16 + (l&15)]
// ---------------------------------------------------------------------------
__global__ void setup_kernel(const float* __restrict__ fc_w,
                             unsigned short* __restrict__ wl,
                             int* __restrict__ bucket_fill, int nbuck)
{
    int o = blockIdx.x * blockDim.x + threadIdx.x;   // 0..32767
    if (o < nbuck) bucket_fill[o] = 0;
    if (o >= 32768) return;
    int j  = o & 7;
    int l  = (o >> 3) & 63;
    int kf = (o >> 9) & 7;
    int cf = (o >> 12) & 7;
    int k   = kf * 32 + (l >> 4) * 8 + j;
    int col = cf * 16 + (l & 15);
    int hh = col >> 5, d = col & 31;
    wl[o] = f2bf(fc_w[hh * 8192 + k * 32 + d]);
}

// ---------------------------------------------------------------------------
// FUSED kernel: blocks [0, nA) run bucketA (CSR scatter, LDS-aggregated);
// blocks [nA, nA+nG) run the MFMA GEMM (128 rows/block). The two phases are
// data-independent; fusing them lets the CSR work hide under the GEMM's
// latency slack instead of serializing on the stream.
// 512 threads; 64 KB LDS union.
// ---------------------------------------------------------------------------
__global__ __launch_bounds__(512, 4) void fused_kernel(
    // gemm args
    const float* __restrict__ h, const unsigned short* __restrict__ wl,
    const float* __restrict__ attn_w,
    unsigned int* __restrict__ zb,
    float* __restrict__ s_src, float* __restrict__ s_dst,
    int n_nodes,
    // bucketA args
    const int* __restrict__ src, const int* __restrict__ dst,
    int* __restrict__ bucket_fill, unsigned int* __restrict__ scratch,
    int n_edges, int nbuck, int nA)
{
    __shared__ __align__(16) char smem[65536];
    const int t = threadIdx.x;

    if (blockIdx.x < nA) {
        // ----------------- bucketA path (512 threads) -----------------
        int* bhist = (int*)smem;                  //  2 KB
        int* boff  = (int*)(smem + 2048);         //  2 KB
        int* goff  = (int*)(smem + 4096);         //  2 KB
        int* bcur  = (int*)(smem + 6144);         //  2 KB
        int* stmp  = (int*)(smem + 8192);         //  2 KB
        unsigned int* lpair = (unsigned int*)(smem + 10240);   // 32 KB

        const int e0 = blockIdx.x * CHUNK;
        const int n  = min(CHUNK, n_edges - e0);

        bhist[t] = 0;
        __syncthreads();

        for (int i = t; i < n; i += 512) {
            atomicAdd(&bhist[dst[e0 + i] >> BSHIFT], 1);
        }
        __syncthreads();

        // exclusive scan over 512 bins, 1 elem/thread
        int v = bhist[t];
        int x = v;
        stmp[t] = x;
        __syncthreads();
        for (int off = 1; off < 512; off <<= 1) {
            int y = (t >= off) ? stmp[t - off] : 0;
            __syncthreads();
            x += y;
            stmp[t] = x;
            __syncthreads();
        }
        int excl = x - v;
        boff[t] = excl;
        bcur[t] = excl;

        // reserve global space (one atomic per non-empty bucket)
        goff[t] = (v > 0 && t < nbuck) ? (t * CAP + atomicAdd(&bucket_fill[t], v)) : 0;
        __syncthreads();

        // stage pairs into LDS grouped by bucket
        for (int i = t; i < n; i += 512) {
            int d  = dst[e0 + i];
            int sv = src[e0 + i];
            int p  = atomicAdd(&bcur[d >> BSHIFT], 1);
            lpair[p] = ((unsigned int)d << 16) | (unsigned int)sv;
        }
        __syncthreads();

        // dense write-out
        const int lim = nbuck * CAP - 1;
        for (int i = t; i < n; i += 512) {
            unsigned int u = lpair[i];
            int b = (int)(u >> 16) >> BSHIFT;
            int addr = goff[b] + (i - boff[b]);
            scratch[min(addr, lim)] = u;
        }
        return;
    }

    // ----------------- gemm path (512 threads, 128 rows/block) -----------------
    unsigned short* wls = (unsigned short*)smem;   // 64 KB

    #pragma unroll
    for (int it = 0; it < 8; ++it) {
        ((uint4*)wls)[t + it * 512] = ((const uint4*)wl)[t + it * 512];
    }
    __syncthreads();

    const int w  = t >> 6;          // wave 0..7
    const int l  = t & 63;
    const int g  = l >> 4;
    const int ln = l & 15;
    const int m0 = (blockIdx.x - nA) * 128 + w * 16;

    const int arow = min(m0 + ln, n_nodes - 1);
    const float4* hrow = (const float4*)(h + (size_t)arow * IN_DIM);

    f32x4 acc[8];
    #pragma unroll
    for (int cf = 0; cf < 8; ++cf) acc[cf] = (f32x4){0.f, 0.f, 0.f, 0.f};

    #pragma unroll
    for (int kf = 0; kf < 8; ++kf) {
        float4 alo = hrow[kf * 8 + g * 2];
        float4 ahi = hrow[kf * 8 + g * 2 + 1];
        union { unsigned int u[4]; bf16x8 v; } fa;
        fa.u[0] = pack_bf2(alo.x, alo.y);
        fa.u[1] = pack_bf2(alo.z, alo.w);
        fa.u[2] = pack_bf2(ahi.x, ahi.y);
        fa.u[3] = pack_bf2(ahi.z, ahi.w);

        #pragma unroll
        for (int cf = 0; cf < 8; ++cf) {
            bf16x8 fb = *(const bf16x8*)&wls[((cf * 8 + kf) * 64 + l) * 8];
            acc[cf] = __builtin_amdgcn_mfma_f32_16x16x32_bf16(fa.v, fb, acc[cf], 0, 0, 0);
        }
    }

    float aw_s[8], aw_d[8];
    #pragma unroll
    for (int cf = 0; cf < 8; ++cf) {
        int col = cf * 16 + ln;
        int hh = col >> 5, d = col & 31;
        aw_s[cf] = attn_w[hh * 64 + d];
        aw_d[cf] = attn_w[hh * 64 + 32 + d];
    }

    #pragma unroll
    for (int r = 0; r < 4; ++r) {
        const int row = m0 + 4 * g + r;
        const bool ok = (row < n_nodes);

        float vs0 = acc[0][r] * aw_s[0] + acc[1][r] * aw_s[1];
        float vs1 = acc[2][r] * aw_s[2] + acc[3][r] * aw_s[3];
        float vs2 = acc[4][r] * aw_s[4] + acc[5][r] * aw_s[5];
        float vs3 = acc[6][r] * aw_s[6] + acc[7][r] * aw_s[7];
        float vd0 = acc[0][r] * aw_d[0] + acc[1][r] * aw_d[1];
        float vd1 = acc[2][r] * aw_d[2] + acc[3][r] * aw_d[3];
        float vd2 = acc[4][r] * aw_d[4] + acc[5][r] * aw_d[5];
        float vd3 = acc[6][r] * aw_d[6] + acc[7][r] * aw_d[7];
        #pragma unroll
        for (int mk = 1; mk < 16; mk <<= 1) {
            vs0 += __shfl_xor(vs0, mk); vs1 += __shfl_xor(vs1, mk);
            vs2 += __shfl_xor(vs2, mk); vs3 += __shfl_xor(vs3, mk);
            vd0 += __shfl_xor(vd0, mk); vd1 += __shfl_xor(vd1, mk);
            vd2 += __shfl_xor(vd2, mk); vd3 += __shfl_xor(vd3, mk);
        }
        float sel_s = (ln == 0) ? vs0 : (ln == 1) ? vs1 : (ln == 2) ? vs2 : vs3;
        float sel_d = ((ln & 3) == 0) ? vd0 : ((ln & 3) == 1) ? vd1 : ((ln & 3) == 2) ? vd2 : vd3;
        if (ok && ln < 4)              s_src[row * N_HEADS + ln]       = sel_s;
        if (ok && ln >= 4 && ln < 8)   s_dst[row * N_HEADS + (ln & 3)] = sel_d;

        #pragma unroll
        for (int cf = 0; cf < 8; ++cf) {
            float v = acc[cf][r];
            float o = __shfl_xor(v, 1);
            if (!(ln & 1) && ok) {
                zb[(size_t)row * 64 + cf * 8 + (ln >> 1)] = pack_bf2(v, o);
            }
        }
    }
}

// ---------------------------------------------------------------------------
// Pass B: one block per bucket, pure LDS work + dense writes. Redundant
// bucket scan -> row0; per-node LDS histogram + scan -> row_start; placement
// writes plain src into sorted_src.
// ---------------------------------------------------------------------------
__global__ __launch_bounds__(256) void bucketB_kernel(
    const unsigned int* __restrict__ scratch,
    const int* __restrict__ bucket_fill,
    int* __restrict__ row_start,
    int* __restrict__ sorted_src,
    int n_nodes, int nbuck, int n_edges)
{
    __shared__ int pref[512];
    __shared__ int lhist[128];
    __shared__ int lcur[128];
    __shared__ int stmp[256];
    __shared__ unsigned int ent[CAP];   // 16 KB

    const int b = blockIdx.x;
    const int t = threadIdx.x;

    // --- redundant exclusive scan of bucket_fill -> pref[] ---
    {
        int a0 = (2 * t     < nbuck) ? min(bucket_fill[2 * t],     CAP) : 0;
        int a1 = (2 * t + 1 < nbuck) ? min(bucket_fill[2 * t + 1], CAP) : 0;
        int s = a0 + a1;
        int x = s;
        stmp[t] = x;
        __syncthreads();
        for (int off = 1; off < 256; off <<= 1) {
            int y = (t >= off) ? stmp[t - off] : 0;
            __syncthreads();
            x += y;
            stmp[t] = x;
            __syncthreads();
        }
        int excl = x - s;
        pref[2 * t]     = excl;
        pref[2 * t + 1] = excl + a0;
    }
    __syncthreads();

    const int cnt_b = min(bucket_fill[b], CAP);
    const int row0  = pref[b];
    const unsigned int* sb = scratch + (size_t)b * CAP;

    if (b == 0 && t == 0) row_start[n_nodes] = n_edges;

    if (t < 128) lhist[t] = 0;
    __syncthreads();

    for (int i = t; i < cnt_b; i += 256) {
        unsigned int u = sb[i];
        ent[i] = u;
        atomicAdd(&lhist[(u >> 16) & (BUCK_NODES - 1)], 1);
    }
    __syncthreads();

    int v = (t < 128) ? lhist[t] : 0;
    int x = v;
    stmp[t] = x;
    __syncthreads();
    for (int off = 1; off < 128; off <<= 1) {
        int y = (t >= off) ? stmp[t - off] : 0;
        __syncthreads();
        x += y;
        stmp[t] = x;
        __syncthreads();
    }
    if (t < 128) {
        int excl = x - v;
        lcur[t] = excl;
        int node = b * BUCK_NODES + t;
        if (node < n_nodes) row_start[node] = row0 + excl;
    }
    __syncthreads();

    for (int i = t; i < cnt_b; i += 256) {
        unsigned int u = ent[i];
        int dl = (u >> 16) & (BUCK_NODES - 1);
        int r = atomicAdd(&lcur[dl], 1);
        sorted_src[row0 + r] = (int)(u & 0xFFFFu);
    }
}

// ---------------------------------------------------------------------------
// fused single-pass softmax + aggregate. TWO nodes per wave:
// lanes 0-31 -> node 2*wid, lanes 32-63 -> node 2*wid+1.
// Per node: 2 edge slots (lane bit 4) x 4-deep unroll = 8 edges in flight.
// Lane owns 8 cols (uint4 of bf16x2).
// ---------------------------------------------------------------------------
__global__ __launch_bounds__(256) void gather_kernel(
    const int* __restrict__ sorted_src, const int* __restrict__ row_start,
    const unsigned int* __restrict__ zb,
    const float* __restrict__ s_src, const float* __restrict__ s_dst,
    float* __restrict__ out, int n_nodes)
{
    int wave = (blockIdx.x * 256 + threadIdx.x) >> 6;
    int lane = threadIdx.x & 63;
    int half = lane >> 5;
    int node = wave * 2 + half;
    int g2   = (lane >> 4) & 1;      // edge slot 0..1
    int q    = lane & 15;            // col group: cols 8q..8q+7
    int hh   = q >> 2;               // head

    const bool valid = (node < n_nodes);
    const int nclamp = min(node, n_nodes - 1);
    const int b0 = row_start[nclamp];
    int deg = row_start[nclamp + 1] - b0;
    if (!valid) deg = 0;

    f32x2 acc2[4];
    #pragma unroll
    for (int i = 0; i < 4; ++i) acc2[i] = (f32x2){0.f, 0.f};
    float den = 0.0f;

    if (deg > 0) {
        const int* sp = sorted_src + b0;
        const float sdst = s_dst[nclamp * N_HEADS + hh];
        const int dm1 = deg - 1;

        for (int p = 0; p < deg; p += 8) {
            int i0 = p + g2, i1 = p + 2 + g2, i2 = p + 4 + g2, i3 = p + 6 + g2;
            int s0 = sp[min(i0, dm1)];
            int s1 = sp[min(i1, dm1)];
            int s2 = sp[min(i2, dm1)];
            int s3 = sp[min(i3, dm1)];

            float f0 = s_src[s0 * N_HEADS + hh];
            float f1 = s_src[s1 * N_HEADS + hh];
            float f2 = s_src[s2 * N_HEADS + hh];
            float f3 = s_src[s3 * N_HEADS + hh];
            uint4 u0 = *(const uint4*)&zb[(size_t)s0 * 64 + q * 4];
            uint4 u1 = *(const uint4*)&zb[(size_t)s1 * 64 + q * 4];
            uint4 u2 = *(const uint4*)&zb[(size_t)s2 * 64 + q * 4];
            uint4 u3 = *(const uint4*)&zb[(size_t)s3 * 64 + q * 4];

            float e0 = f0 + sdst; e0 = fmaxf(e0, NEG_SLOPE * e0);
            float e1 = f1 + sdst; e1 = fmaxf(e1, NEG_SLOPE * e1);
            float e2 = f2 + sdst; e2 = fmaxf(e2, NEG_SLOPE * e2);
            float e3 = f3 + sdst; e3 = fmaxf(e3, NEG_SLOPE * e3);
            float x0 = (i0 <= dm1) ? __expf(e0) : 0.0f;
            float x1 = (i1 <= dm1) ? __expf(e1) : 0.0f;
            float x2 = (i2 <= dm1) ? __expf(e2) : 0.0f;
            float x3 = (i3 <= dm1) ? __expf(e3) : 0.0f;
            den += (x0 + x1) + (x2 + x3);

            f32x2 xv;
            xv = (f32x2){x0, x0};
            acc2[0] += xv * bfpair(u0.x);
            acc2[1] += xv * bfpair(u0.y);
            acc2[2] += xv * bfpair(u0.z);
            acc2[3] += xv * bfpair(u0.w);
            xv = (f32x2){x1, x1};
            acc2[0] += xv * bfpair(u1.x);
            acc2[1] += xv * bfpair(u1.y);
            acc2[2] += xv * bfpair(u1.z);
            acc2[3] += xv * bfpair(u1.w);
            xv = (f32x2){x2, x2};
            acc2[0] += xv * bfpair(u2.x);
            acc2[1] += xv * bfpair(u2.y);
            acc2[2] += xv * bfpair(u2.z);
            acc2[3] += xv * bfpair(u2.w);
            xv = (f32x2){x3, x3};
            acc2[0] += xv * bfpair(u3.x);
            acc2[1] += xv * bfpair(u3.y);
            acc2[2] += xv * bfpair(u3.z);
            acc2[3] += xv * bfpair(u3.w);
        }
    }

    // reduce across the 2 edge slots (lane bit 4; stays within 32-lane half)
    #pragma unroll
    for (int i = 0; i < 4; ++i) {
        acc2[i].x += __shfl_xor(acc2[i].x, 16);
        acc2[i].y += __shfl_xor(acc2[i].y, 16);
    }
    den += __shfl_xor(den, 16);

    if (g2 == 0 && valid) {
        float inv = (deg > 0) ? 1.0f / den : 0.0f;
        float4 v0 = make_float4(acc2[0].x * inv, acc2[0].y * inv, acc2[1].x * inv, acc2[1].y * inv);
        float4 v1 = make_float4(acc2[2].x * inv, acc2[2].y * inv, acc2[3].x * inv, acc2[3].y * inv);
        float4* op = (float4*)&out[(size_t)node * OUT_DIM + q * 8];
        op[0] = v0;
        op[1] = v1;
    }
}

// ---------------------------------------------------------------------------
extern "C" void kernel_launch(void* const* d_in, const int* in_sizes, int n_in,
                              void* d_out, int out_size, void* d_ws, size_t ws_size,
                              hipStream_t stream)
{
    const float* h      = (const float*)d_in[0];
    const float* fc_w   = (const float*)d_in[1];
    const float* attn_w = (const float*)d_in[2];
    const int*   src    = (const int*)d_in[3];
    const int*   dst    = (const int*)d_in[4];

    const int n_nodes = in_sizes[0] / IN_DIM;   // 50000
    const int n_edges = in_sizes[3];            // 800000
    const int nbuck   = (n_nodes + BUCK_NODES - 1) / BUCK_NODES;   // 391

    float* out = (float*)d_out;

    // workspace layout (all 4-byte types, 16B-aligned blocks)
    char* ws = (char*)d_ws;
    unsigned int* zb      = (unsigned int*)ws;                          // n_nodes*64 u32
    float* s_src          = (float*)(zb + (size_t)n_nodes * 64);        // n_nodes*4
    float* s_dst          = s_src + (size_t)n_nodes * N_HEADS;          // n_nodes*4
    int*   row_start      = (int*)(s_dst + (size_t)n_nodes * N_HEADS);  // n_nodes+1 (+pad)
    int*   bucket_fill    = row_start + n_nodes + 16;                   // nbuck
    int*   sorted_src     = bucket_fill + nbuck + 17;                   // n_edges
    unsigned int* scratch = (unsigned int*)(sorted_src + n_edges + 16); // nbuck*CAP
    unsigned short* wl_g  = (unsigned short*)(scratch + (size_t)nbuck * CAP); // 32768 bf16

    const int nA = (n_edges + CHUNK - 1) / CHUNK;        // 98 bucketA blocks
    const int nG = (n_nodes + 127) / 128;                // 391 gemm blocks

    // 1. setup: W prep + zero bucket_fill
    setup_kernel<<<128, 256, 0, stream>>>(fc_w, wl_g, bucket_fill, nbuck);

    // 2. FUSED: bucketA (CSR scatter) overlapped with MFMA GEMM
    fused_kernel<<<nA + nG, 512, 0, stream>>>(
        h, wl_g, attn_w, zb, s_src, s_dst, n_nodes,
        src, dst, bucket_fill, scratch, n_edges, nbuck, nA);

    // 3. bucket pass B: CSR finalize (pure LDS + dense writes)
    bucketB_kernel<<<nbuck, 256, 0, stream>>>(
        scratch, bucket_fill, row_start, sorted_src, n_nodes, nbuck, n_edges);

    // 4. fused single-pass softmax + aggregate, 2 consecutive nodes per wave
    {
        int waves = (n_nodes + 1) / 2;
        int blocks = (waves * 64 + 255) / 256;
        gather_kernel<<<blocks, 256, 0, stream>>>(
            sorted_src, row_start, zb, s_src, s_dst, out, n_nodes);
    }
}